// Round 10
// baseline (859.345 us; speedup 1.0000x reference)
//
#include <hip/hip_runtime.h>
#include <hip/hip_bf16.h>

// NGCF forward, MI355X. Sizes fixed by the problem.
constexpr int N_NODES = 300000;   // N_USERS + N_ITEMS
constexpr int DIM = 64;

// Bucketed CSR build parameters
constexpr int CHUNK  = 8192;            // edges per binning block
constexpr int B_ROWS = 256;             // rows per bucket (bucket = row >> 8)
constexpr int NB_B   = (N_NODES + B_ROWS - 1) / B_ROWS;   // 1172 buckets
constexpr int CAP    = 12288;           // max edges/bucket in bucketfinal LDS
constexpr int SCAN_B = 4096;            // elements per scan1 block (16/thread)
constexpr int COL_MASK = (1 << 19) - 1; // col < 2^19 (300000 < 524288)

typedef unsigned short ushort_t;
typedef unsigned char  uchar_t;
typedef __attribute__((ext_vector_type(8))) short bf16x8;
typedef __attribute__((ext_vector_type(4))) float f32x4;
typedef __attribute__((ext_vector_type(2))) float f32x2;

__device__ __forceinline__ float blo(unsigned u) { return __uint_as_float(u << 16); }
__device__ __forceinline__ float bhi(unsigned u) { return __uint_as_float(u & 0xffff0000u); }
__device__ __forceinline__ ushort_t f2b(float f) {            // fp32 -> bf16 (RNE)
    unsigned u = __float_as_uint(f);
    return (ushort_t)((u + 0x7fffu + ((u >> 16) & 1u)) >> 16);
}

// ---- fp8 e4m3fn helpers (OCP on gfx950). HI must be compile-time const. ----
template<bool HI>
__device__ __forceinline__ f32x2 f8cvt2(unsigned u) {
#if __has_builtin(__builtin_amdgcn_cvt_pk_f32_fp8)
    return __builtin_amdgcn_cvt_pk_f32_fp8((int)u, HI);
#else
    unsigned b0 = (u >> (HI ? 16 : 0)) & 0xffu, b1 = (u >> (HI ? 24 : 8)) & 0xffu;
    f32x2 r;
    r[0] = __uint_as_float(((b0 & 0x80u) << 24) | ((b0 & 0x7fu) << 20)) * 0x1p120f;
    r[1] = __uint_as_float(((b1 & 0x80u) << 24) | ((b1 & 0x7fu) << 20)) * 0x1p120f;
    return r;
#endif
}

__device__ __forceinline__ unsigned sw_e4m3(float f) {        // fallback encode (RNE)
    unsigned u = __float_as_uint(f);
    unsigned s = (u >> 24) & 0x80u;
    float a = fabsf(f);
    if (a >= 464.f) return s | 0x7eu;
    int E = (int)((u >> 23) & 0xff) - 120;      // e4m3 biased exp
    if (E >= 1) {
        unsigned m = u & 0x7fffffu;
        unsigned keep = m >> 20;
        unsigned rest = m & 0xfffffu;
        keep += (rest > 0x80000u || (rest == 0x80000u && (keep & 1u))) ? 1u : 0u;
        if (keep == 8u) { keep = 0u; E += 1; }
        if (E > 15 || (E == 15 && keep > 6u)) return s | 0x7eu;
        return s | ((unsigned)E << 3) | keep;
    } else {
        int q = (int)rintf(a * 512.f);
        if (q > 7) return s | 0x08u;
        return s | (unsigned)q;
    }
}

__device__ __forceinline__ unsigned f8pack4(float a, float b, float c, float d) {
#if __has_builtin(__builtin_amdgcn_cvt_pk_fp8_f32)
    int r = 0;
    r = __builtin_amdgcn_cvt_pk_fp8_f32(a, b, r, false);
    r = __builtin_amdgcn_cvt_pk_fp8_f32(c, d, r, true);
    return (unsigned)r;
#else
    return sw_e4m3(a) | (sw_e4m3(b) << 8) | (sw_e4m3(c) << 16) | (sw_e4m3(d) << 24);
#endif
}

__device__ __forceinline__ uchar_t f8pack1(float a) {
#if __has_builtin(__builtin_amdgcn_cvt_pk_fp8_f32)
    int r = __builtin_amdgcn_cvt_pk_fp8_f32(a, 0.f, 0, false);
    return (uchar_t)(r & 0xff);
#else
    return (uchar_t)sw_e4m3(a);
#endif
}

// ---------------------------------------------------------------------------
// k1: per-chunk bucket histogram. histT[chunk][b] (coalesced write).
// ---------------------------------------------------------------------------
__global__ __launch_bounds__(256) void binhist_kernel(
    const int* __restrict__ rows, int* __restrict__ histT, int nnz)
{
    __shared__ int cnt[NB_B];
    for (int i = threadIdx.x; i < NB_B; i += 256) cnt[i] = 0;
    __syncthreads();
    int base = blockIdx.x * CHUNK;
#pragma unroll
    for (int k = 0; k < CHUNK / 256; ++k) {
        int e = base + k * 256 + threadIdx.x;
        if (e < nnz) atomicAdd(&cnt[rows[e] >> 8], 1);
    }
    __syncthreads();
    for (int b = threadIdx.x; b < NB_B; b += 256)
        histT[(size_t)blockIdx.x * NB_B + b] = cnt[b];
}

// 32x32 tiled transpose: in[R][C] -> out[C][R]
__global__ __launch_bounds__(256) void transpose_kernel(
    const int* __restrict__ in, int* __restrict__ out, int R, int C)
{
    __shared__ int tile[32][33];
    int c0 = blockIdx.x * 32, r0 = blockIdx.y * 32;
    int tx = threadIdx.x & 31, ty = threadIdx.x >> 5;
#pragma unroll
    for (int k = 0; k < 4; ++k) {
        int r = r0 + ty + k * 8, c = c0 + tx;
        if (r < R && c < C) tile[ty + k * 8][tx] = in[(size_t)r * C + c];
    }
    __syncthreads();
#pragma unroll
    for (int k = 0; k < 4; ++k) {
        int c = c0 + ty + k * 8, r = r0 + tx;
        if (c < C && r < R) out[(size_t)c * R + r] = tile[tx][ty + k * 8];
    }
}

// ---------------------------------------------------------------------------
// Exclusive scan over n elements (in place).
// ---------------------------------------------------------------------------
__global__ __launch_bounds__(256) void scan1_kernel(
    int* __restrict__ a, int* __restrict__ bsum, int n)
{
    __shared__ int tsum[256];
    int base = blockIdx.x * SCAN_B;
    int v[16];
    int s = 0;
#pragma unroll
    for (int k = 0; k < 16; ++k) {
        int i = base + threadIdx.x * 16 + k;
        v[k] = (i < n) ? a[i] : 0;
        s += v[k];
    }
    tsum[threadIdx.x] = s;
    __syncthreads();
    for (int off = 1; off < 256; off <<= 1) {
        int u = (threadIdx.x >= off) ? tsum[threadIdx.x - off] : 0;
        __syncthreads();
        tsum[threadIdx.x] += u;
        __syncthreads();
    }
    int excl = (threadIdx.x == 0) ? 0 : tsum[threadIdx.x - 1];
#pragma unroll
    for (int k = 0; k < 16; ++k) {
        int i = base + threadIdx.x * 16 + k;
        if (i < n) a[i] = excl;
        excl += v[k];
    }
    if (threadIdx.x == 255) bsum[blockIdx.x] = tsum[255];
}

__global__ __launch_bounds__(256) void scan2_kernel(int* bsum, int nb)   // nb <= 2048
{
    __shared__ int tsum[256];
    int v[8];
    int s = 0;
#pragma unroll
    for (int k = 0; k < 8; ++k) {
        int i = threadIdx.x * 8 + k;
        v[k] = (i < nb) ? bsum[i] : 0;
        s += v[k];
    }
    tsum[threadIdx.x] = s;
    __syncthreads();
    for (int off = 1; off < 256; off <<= 1) {
        int u = (threadIdx.x >= off) ? tsum[threadIdx.x - off] : 0;
        __syncthreads();
        tsum[threadIdx.x] += u;
        __syncthreads();
    }
    int excl = (threadIdx.x == 0) ? 0 : tsum[threadIdx.x - 1];
#pragma unroll
    for (int k = 0; k < 8; ++k) {
        int i = threadIdx.x * 8 + k;
        if (i < nb) bsum[i] = excl;
        excl += v[k];
    }
}

__global__ __launch_bounds__(256) void scan3_kernel(
    int* __restrict__ a, const int* __restrict__ bsum, int n)
{
    int i = blockIdx.x * 256 + threadIdx.x;
    if (i < n) a[i] += bsum[i >> 12];    // SCAN_B = 4096
}

// ---------------------------------------------------------------------------
// k5: binned scatter — LDS counting-sort of the chunk, then ordered flush.
// Payload packed: x = col | (local_row << 19), y = val bits.
// ---------------------------------------------------------------------------
__global__ __launch_bounds__(512) void binscatter_kernel(
    const int* __restrict__ rows, const int* __restrict__ cols,
    const float* __restrict__ vals, const int* __restrict__ curT,
    int2* __restrict__ meta, int nnz)
{
    __shared__ int2 cv[CHUNK];      // 64 KB  sorted payload
    __shared__ int  dst[CHUNK];     // 32 KB  global destination per slot
    __shared__ int  cnt[NB_B];      // hist, then per-bucket cursor
    __shared__ int  loc[NB_B];      // local exclusive offsets
    __shared__ int  gb[NB_B];       // global bases for this chunk
    __shared__ int  tsum[512];

    const int tid  = threadIdx.x;
    const int base = blockIdx.x * CHUNK;

    for (int b = tid; b < NB_B; b += 512) cnt[b] = 0;
    __syncthreads();

    int rb[16], pk[16], vb[16];
#pragma unroll
    for (int k = 0; k < 16; ++k) {
        int e = base + k * 512 + tid;
        if (e < nnz) {
            int r = rows[e];
            rb[k] = r >> 8;
            pk[k] = cols[e] | ((r & 255) << 19);
            vb[k] = __float_as_int(vals[e]);
            atomicAdd(&cnt[rb[k]], 1);
        } else rb[k] = -1;
    }
    __syncthreads();

    int i0 = tid * 3;
    int c0 = 0, c1 = 0, c2 = 0, s = 0;
    if (i0     < NB_B) { c0 = cnt[i0];     s += c0; }
    if (i0 + 1 < NB_B) { c1 = cnt[i0 + 1]; s += c1; }
    if (i0 + 2 < NB_B) { c2 = cnt[i0 + 2]; s += c2; }
    tsum[tid] = s;
    __syncthreads();
    for (int off = 1; off < 512; off <<= 1) {
        int u = (tid >= off) ? tsum[tid - off] : 0;
        __syncthreads();
        tsum[tid] += u;
        __syncthreads();
    }
    int ex = (tid == 0) ? 0 : tsum[tid - 1];
    if (i0     < NB_B) { loc[i0]     = ex; ex += c0; }
    if (i0 + 1 < NB_B) { loc[i0 + 1] = ex; ex += c1; }
    if (i0 + 2 < NB_B) { loc[i0 + 2] = ex; ex += c2; }
    __syncthreads();

    for (int b = tid; b < NB_B; b += 512) {
        gb[b]  = curT[(size_t)blockIdx.x * NB_B + b];
        cnt[b] = 0;
    }
    __syncthreads();

#pragma unroll
    for (int k = 0; k < 16; ++k) {
        if (rb[k] >= 0) {
            int b   = rb[k];
            int off = atomicAdd(&cnt[b], 1);
            int p   = loc[b] + off;
            cv[p]   = make_int2(pk[k], vb[k]);
            dst[p]  = gb[b] + off;
        }
    }
    __syncthreads();

    int n = min(nnz - base, CHUNK);
    for (int i = tid; i < n; i += 512)
        meta[dst[i]] = cv[i];
}

// ---------------------------------------------------------------------------
// k6: per-bucket finalize. Builds row_ptr, permutes payload in place.
// ---------------------------------------------------------------------------
__global__ __launch_bounds__(256) void bucketfinal_kernel(
    const int* __restrict__ histS,      // [NB_B][nch] scanned (bucket-major)
    int2* __restrict__ meta,
    int* __restrict__ row_ptr, int nnz, int nch)
{
    __shared__ int2 cv[CAP];            // 96 KB
    __shared__ int cnt[256], scn[256], cur[256];

    int b    = blockIdx.x;
    int base = histS[(size_t)b * nch];
    int end  = (b + 1 < gridDim.x) ? histS[(size_t)(b + 1) * nch] : nnz;
    int n    = min(end - base, CAP);

    cnt[threadIdx.x] = 0;
    __syncthreads();
    for (int i = threadIdx.x; i < n; i += 256) {
        int2 m = meta[base + i];
        cv[i] = m;
        atomicAdd(&cnt[(m.x >> 19) & 255], 1);
    }
    __syncthreads();
    int v = cnt[threadIdx.x];
    scn[threadIdx.x] = v;
    __syncthreads();
    for (int off = 1; off < 256; off <<= 1) {
        int u = (threadIdx.x >= off) ? scn[threadIdx.x - off] : 0;
        __syncthreads();
        scn[threadIdx.x] += u;
        __syncthreads();
    }
    int excl = scn[threadIdx.x] - v;

    int r0 = b * B_ROWS;
    int nr = min(B_ROWS, N_NODES - r0);
    if (threadIdx.x < nr) row_ptr[r0 + threadIdx.x] = base + excl;
    if (b == gridDim.x - 1 && threadIdx.x == 0) row_ptr[N_NODES] = nnz;

    cur[threadIdx.x] = excl;
    __syncthreads();
    for (int i = threadIdx.x; i < n; i += 256) {
        int2 m = cv[i];
        int d = atomicAdd(&cur[(m.x >> 19) & 255], 1);
        meta[base + d] = m;
    }
}

// ---------------------------------------------------------------------------
// emb prep: out[:,0:64] = emb AND fp8 gather table, one pass over emb.
// thread = one float4 (4 dims) -> one packed fp8 uint.
// ---------------------------------------------------------------------------
__global__ __launch_bounds__(256) void emb_prep_kernel(
    const float4* __restrict__ emb, unsigned* __restrict__ tblF8,
    float4* __restrict__ out)
{
    int i = blockIdx.x * 256 + threadIdx.x;
    if (i >= N_NODES * 16) return;
    float4 x = emb[i];
    int n = i >> 4, j = i & 15;
    out[(size_t)n * 48 + j] = x;
    tblF8[i] = f8pack4(x.x, x.y, x.z, x.w);
}

// ---------------------------------------------------------------------------
// CSR SpMM with fp8 e4m3 gather table: one wave per row, 8 edge slots x 8
// dim-eighths (8 B = 8 fp8 per lane -> 64 B/edge, one cache line).
// fp32 accumulate, no atomics.
// ---------------------------------------------------------------------------
__global__ __launch_bounds__(256) void spmm_csr_f8_kernel(
    const uint2* __restrict__ tbl8,     // fp8 rows of 64 B
    const int*   __restrict__ row_ptr,
    const int2*  __restrict__ meta,
    float*       __restrict__ side)
{
    int wid = (blockIdx.x * 256 + threadIdx.x) >> 6;
    if (wid >= N_NODES) return;
    int lane = threadIdx.x & 63;
    int g = lane >> 3;
    int q = lane & 7;

    int start = row_ptr[wid];
    int end   = row_ptr[wid + 1];

    float acc[8];
#pragma unroll
    for (int i = 0; i < 8; ++i) acc[i] = 0.f;

    for (int j = start + g; j < end; j += 8) {
        int2 m = meta[j];
        float v = __int_as_float(m.y);
        uint2 x = tbl8[(size_t)(m.x & COL_MASK) * 8 + q];
        f32x2 f0 = f8cvt2<false>(x.x), f1 = f8cvt2<true>(x.x);
        f32x2 f2 = f8cvt2<false>(x.y), f3 = f8cvt2<true>(x.y);
        acc[0] += v * f0[0]; acc[1] += v * f0[1];
        acc[2] += v * f1[0]; acc[3] += v * f1[1];
        acc[4] += v * f2[0]; acc[5] += v * f2[1];
        acc[6] += v * f3[0]; acc[7] += v * f3[1];
    }
#pragma unroll
    for (int off = 8; off <= 32; off <<= 1) {
#pragma unroll
        for (int i = 0; i < 8; ++i) acc[i] += __shfl_xor(acc[i], off);
    }
    if (g == 0) {
        float4* dst = (float4*)(side + (size_t)wid * DIM + q * 8);
        dst[0] = make_float4(acc[0], acc[1], acc[2], acc[3]);
        dst[1] = make_float4(acc[4], acc[5], acc[6], acc[7]);
    }
}

// ---------------------------------------------------------------------------
// MFMA dense layer: y = leaky(s@gw.T + gb + p@bw.T + bb), s=side+e, p=side*e.
// 64 nodes per block; 4 waves, each owns a 16-node sub-tile. Layer 0 reads
// ego as fp32 (emb input directly); layer 1 reads the bf16 ego table.
// Epilogue (layer 0) writes next-layer tables: bf16 (dense) + fp8 (gather).
// ---------------------------------------------------------------------------
template<bool EGO_F32, bool WRITE_TBL>
__global__ __launch_bounds__(256) void dense_mfma_kernel(
    const float*   __restrict__ ego_f32,    // EGO_F32
    const ushort_t* __restrict__ ego_b16,   // !EGO_F32
    const float* __restrict__ side,
    const float* __restrict__ gw, const float* __restrict__ gb,
    const float* __restrict__ bw, const float* __restrict__ bb,
    ushort_t* __restrict__ tblb_out,        // bf16 ego out (layer 0)
    uchar_t*  __restrict__ tblf8_out,       // fp8 ego out (layer 0)
    float* __restrict__ out, int out_col)
{
    __shared__ ushort_t s_lds[64][72];      // 9 KB (pad 8 bf16 = 16 B)
    __shared__ ushort_t p_lds[64][72];      // 9 KB

    const int tid  = threadIdx.x;
    const int lane = tid & 63;
    const int wv   = tid >> 6;
    const int lrow = lane & 15;
    const int kgrp = lane >> 4;

    // B-fragments (weights) + bias, loaded once
    bf16x8 wgf[4][2], wbf[4][2];
    float  biasv[4];
#pragma unroll
    for (int t = 0; t < 4; ++t) {
        int o = 16 * t + lrow;
#pragma unroll
        for (int h = 0; h < 2; ++h) {
            const float* pg = gw + (size_t)o * DIM + 32 * h + 8 * kgrp;
            const float* pb = bw + (size_t)o * DIM + 32 * h + 8 * kgrp;
            ushort_t tg[8], tb[8];
#pragma unroll
            for (int i = 0; i < 8; ++i) { tg[i] = f2b(pg[i]); tb[i] = f2b(pb[i]); }
            wgf[t][h] = *(const bf16x8*)tg;
            wbf[t][h] = *(const bf16x8*)tb;
        }
        biasv[t] = gb[o] + bb[o];
    }

    for (int tile0 = blockIdx.x * 64; tile0 < N_NODES; tile0 += gridDim.x * 64) {
        int nmax = min(64, N_NODES - tile0);
        __syncthreads();
        // ---- stage s,p (bf16) for 64 nodes: thread = (row, dim-quarter) ----
        {
            int r  = tid >> 2;
            int d0 = (tid & 3) * 16;
            if (r < nmax) {
                const float4* sp = (const float4*)(side + (size_t)(tile0 + r) * DIM + d0);
                float4 s0 = sp[0], s1 = sp[1], s2 = sp[2], s3 = sp[3];
                float sv[16] = { s0.x, s0.y, s0.z, s0.w, s1.x, s1.y, s1.z, s1.w,
                                 s2.x, s2.y, s2.z, s2.w, s3.x, s3.y, s3.z, s3.w };
                float ev[16];
                if (EGO_F32) {
                    const float4* ep = (const float4*)(ego_f32 + (size_t)(tile0 + r) * DIM + d0);
                    float4 e0 = ep[0], e1 = ep[1], e2 = ep[2], e3 = ep[3];
                    float tmp[16] = { e0.x, e0.y, e0.z, e0.w, e1.x, e1.y, e1.z, e1.w,
                                      e2.x, e2.y, e2.z, e2.w, e3.x, e3.y, e3.z, e3.w };
#pragma unroll
                    for (int i = 0; i < 16; ++i) ev[i] = tmp[i];
                } else {
                    const uint4* ep = (const uint4*)(ego_b16 + (size_t)(tile0 + r) * DIM + d0);
                    uint4 e0 = ep[0], e1 = ep[1];
                    float tmp[16] = { blo(e0.x), bhi(e0.x), blo(e0.y), bhi(e0.y),
                                      blo(e0.z), bhi(e0.z), blo(e0.w), bhi(e0.w),
                                      blo(e1.x), bhi(e1.x), blo(e1.y), bhi(e1.y),
                                      blo(e1.z), bhi(e1.z), blo(e1.w), bhi(e1.w) };
#pragma unroll
                    for (int i = 0; i < 16; ++i) ev[i] = tmp[i];
                }
                unsigned spk[8], ppk[8];
#pragma unroll
                for (int i = 0; i < 8; ++i) {
                    float a  = sv[2*i]   + ev[2*i];
                    float b2 = sv[2*i+1] + ev[2*i+1];
                    float c  = sv[2*i]   * ev[2*i];
                    float d  = sv[2*i+1] * ev[2*i+1];
                    spk[i] = ((unsigned)f2b(b2) << 16) | f2b(a);
                    ppk[i] = ((unsigned)f2b(d)  << 16) | f2b(c);
                }
                *(uint4*)&s_lds[r][d0]     = make_uint4(spk[0], spk[1], spk[2], spk[3]);
                *(uint4*)&s_lds[r][d0 + 8] = make_uint4(spk[4], spk[5], spk[6], spk[7]);
                *(uint4*)&p_lds[r][d0]     = make_uint4(ppk[0], ppk[1], ppk[2], ppk[3]);
                *(uint4*)&p_lds[r][d0 + 8] = make_uint4(ppk[4], ppk[5], ppk[6], ppk[7]);
            }
        }
        __syncthreads();

        // ---- compute: wave wv owns nodes tile0 + wv*16 .. +15 ----
        const int arow = wv * 16 + lrow;
        bf16x8 sf[2], pf[2];
        sf[0] = *(const bf16x8*)&s_lds[arow][8 * kgrp];
        sf[1] = *(const bf16x8*)&s_lds[arow][32 + 8 * kgrp];
        pf[0] = *(const bf16x8*)&p_lds[arow][8 * kgrp];
        pf[1] = *(const bf16x8*)&p_lds[arow][32 + 8 * kgrp];

        f32x4 acc[4];
#pragma unroll
        for (int t = 0; t < 4; ++t)
            acc[t] = (f32x4){biasv[t], biasv[t], biasv[t], biasv[t]};

#pragma unroll
        for (int h = 0; h < 2; ++h) {
#pragma unroll
            for (int t = 0; t < 4; ++t) {
                acc[t] = __builtin_amdgcn_mfma_f32_16x16x32_bf16(sf[h], wgf[t][h], acc[t], 0, 0, 0);
                acc[t] = __builtin_amdgcn_mfma_f32_16x16x32_bf16(pf[h], wbf[t][h], acc[t], 0, 0, 0);
            }
        }

        // ---- epilogue: leaky, row-norm (16-lane group reduce), stores ----
        float y[4][4];
        float ssr[4] = {0.f, 0.f, 0.f, 0.f};
#pragma unroll
        for (int t = 0; t < 4; ++t)
#pragma unroll
            for (int rg = 0; rg < 4; ++rg) {
                float v = acc[t][rg];
                v = v > 0.f ? v : 0.2f * v;
                y[t][rg] = v;
                ssr[rg] += v * v;
            }
#pragma unroll
        for (int off = 1; off <= 8; off <<= 1)
#pragma unroll
            for (int rg = 0; rg < 4; ++rg)
                ssr[rg] += __shfl_xor(ssr[rg], off);

#pragma unroll
        for (int rg = 0; rg < 4; ++rg) {
            int node = tile0 + wv * 16 + kgrp * 4 + rg;
            if (node < N_NODES) {
                float inv = 1.0f / fmaxf(sqrtf(ssr[rg]), 1e-12f);
                float* orow = out + (size_t)node * 192 + out_col;
#pragma unroll
                for (int t = 0; t < 4; ++t)
                    orow[t * 16 + lrow] = y[t][rg] * inv;
                if (WRITE_TBL) {
#pragma unroll
                    for (int t = 0; t < 4; ++t) {
                        tblb_out[(size_t)node * DIM + t * 16 + lrow] = f2b(y[t][rg]);
                        tblf8_out[(size_t)node * DIM + t * 16 + lrow] = f8pack1(y[t][rg]);
                    }
                }
            }
        }
    }
}

// ---------------------------------------------------------------------------
// Fallback path (ws too small): atomic SpMM + fp32 dense.
// ---------------------------------------------------------------------------
__global__ __launch_bounds__(256) void spmm_atomic_kernel(
    const float* __restrict__ ego,
    const int*   __restrict__ rows,
    const int*   __restrict__ cols,
    const float* __restrict__ vals,
    float*       __restrict__ side,
    int nnz)
{
    long long i = (long long)blockIdx.x * blockDim.x + threadIdx.x;
    long long total = (long long)nnz * DIM;
    if (i >= total) return;
    int e = (int)(i >> 6);
    int d = (int)(i & 63);
    atomicAdd(side + ((size_t)rows[e] * DIM + d), vals[e] * ego[(size_t)cols[e] * DIM + d]);
}

template<bool WRITE_F32>
__global__ __launch_bounds__(256) void dense_norm_kernel(
    const float* __restrict__ ego_in,
    const float* __restrict__ side,
    const float* __restrict__ gw, const float* __restrict__ gb,
    const float* __restrict__ bw, const float* __restrict__ bb,
    float* __restrict__ ego_out,
    float* __restrict__ out, int out_col)
{
    __shared__ float s_lds[32][DIM];
    __shared__ float p_lds[32][DIM];

    const int o  = threadIdx.x & 63;
    const int wv = threadIdx.x >> 6;

    float w0[DIM], w1[DIM];
#pragma unroll
    for (int k4 = 0; k4 < DIM / 4; ++k4) {
        float4 a = *(const float4*)(gw + (size_t)o * DIM + k4 * 4);
        float4 b = *(const float4*)(bw + (size_t)o * DIM + k4 * 4);
        w0[4*k4+0] = a.x; w0[4*k4+1] = a.y; w0[4*k4+2] = a.z; w0[4*k4+3] = a.w;
        w1[4*k4+0] = b.x; w1[4*k4+1] = b.y; w1[4*k4+2] = b.z; w1[4*k4+3] = b.w;
    }
    const float bias = gb[o] + bb[o];

    for (int tile = blockIdx.x * 32; tile < N_NODES; tile += gridDim.x * 32) {
        int nmax = min(32, N_NODES - tile);
        __syncthreads();
        const float4* sd4 = (const float4*)side + (size_t)tile * 16;
        const float4* eg4 = (const float4*)ego_in + (size_t)tile * 16;
        float4* s4 = (float4*)&s_lds[0][0];
        float4* p4 = (float4*)&p_lds[0][0];
        for (int i = threadIdx.x; i < nmax * 16; i += 256) {
            float4 e = eg4[i], s = sd4[i];
            s4[i] = make_float4(s.x+e.x, s.y+e.y, s.z+e.z, s.w+e.w);
            p4[i] = make_float4(s.x*e.x, s.y*e.y, s.z*e.z, s.w*e.w);
        }
        __syncthreads();
        for (int n = wv; n < nmax; n += 4) {
            const float4* srow = (const float4*)&s_lds[n][0];
            const float4* prow = (const float4*)&p_lds[n][0];
            float a0 = bias, a1 = 0.f, a2 = 0.f, a3 = 0.f;
#pragma unroll
            for (int k4 = 0; k4 < 16; ++k4) {
                float4 sk = srow[k4];
                float4 pk = prow[k4];
                a0 = fmaf(sk.x, w0[4*k4+0], a0); a1 = fmaf(pk.x, w1[4*k4+0], a1);
                a2 = fmaf(sk.y, w0[4*k4+1], a2); a3 = fmaf(pk.y, w1[4*k4+1], a3);
                a0 = fmaf(sk.z, w0[4*k4+2], a0); a1 = fmaf(pk.z, w1[4*k4+2], a1);
                a2 = fmaf(sk.w, w0[4*k4+3], a2); a3 = fmaf(pk.w, w1[4*k4+3], a3);
            }
            float acc = (a0 + a1) + (a2 + a3);
            float y = acc > 0.f ? acc : 0.2f * acc;
            size_t node = (size_t)(tile + n);
            if (WRITE_F32) ego_out[node * DIM + o] = y;
            float ss = y * y;
#pragma unroll
            for (int off = 32; off > 0; off >>= 1)
                ss += __shfl_xor(ss, off);
            float inv = 1.0f / fmaxf(sqrtf(ss), 1e-12f);
            out[node * 192 + out_col + o] = y * inv;
        }
    }
}

__global__ __launch_bounds__(256) void copy_emb_kernel(
    const float4* __restrict__ emb, float4* __restrict__ out)
{
    int i = blockIdx.x * blockDim.x + threadIdx.x;
    if (i >= N_NODES * 16) return;
    int n = i >> 4, j = i & 15;
    out[(size_t)n * 48 + j] = emb[i];
}

extern "C" void kernel_launch(void* const* d_in, const int* in_sizes, int n_in,
                              void* d_out, int out_size, void* d_ws, size_t ws_size,
                              hipStream_t stream)
{
    const float* emb   = (const float*)d_in[0];
    const float* gc_w0 = (const float*)d_in[1];
    const float* gc_b0 = (const float*)d_in[2];
    const float* bi_w0 = (const float*)d_in[3];
    const float* bi_b0 = (const float*)d_in[4];
    const float* gc_w1 = (const float*)d_in[5];
    const float* gc_b1 = (const float*)d_in[6];
    const float* bi_w1 = (const float*)d_in[7];
    const float* bi_b1 = (const float*)d_in[8];
    const int*   rows  = (const int*)d_in[9];
    const int*   cols  = (const int*)d_in[10];
    const float* vals  = (const float*)d_in[11];
    const int    nnz   = in_sizes[9];

    float* out = (float*)d_out;

    const int nch = (nnz + CHUNK - 1) / CHUNK;            // chunks
    const int n2  = NB_B * nch;                           // hist entries
    const size_t hist_al = (((size_t)n2 * sizeof(int)) + 63) & ~size_t(63);
    const size_t tbl_al  = (((size_t)N_NODES * DIM) + 63) & ~size_t(63);  // fp8 table bytes

    // ---- workspace layout ----
    char* ws = (char*)d_ws;
    size_t off = 0;
    auto alloc = [&](size_t bytes) { char* p = ws + off; off += (bytes + 63) & ~size_t(63); return p; };
    float* side = (float*)alloc((size_t)N_NODES * DIM * sizeof(float));
    ushort_t* ego1_b = (ushort_t*)alloc((size_t)N_NODES * DIM * sizeof(ushort_t));
    int2* meta = (int2*)alloc((size_t)nnz * sizeof(int2));
    // Union region: build-phase {histT, histA}; post-build {emb_f8 / ego1_f8 (time-shared)}
    size_t u_build = 2 * hist_al;
    char* U = alloc(u_build > tbl_al ? u_build : tbl_al);
    int* histT = (int*)U;
    int* histA = (int*)(U + hist_al);
    int* curT  = histT;                                   // reuse after transpose 1
    uchar_t* emb_f8  = (uchar_t*)U;                       // alive: emb_prep..spmm0
    uchar_t* ego1_f8 = (uchar_t*)U;                       // alive: dense0..spmm1
    int* row_ptr = (int*)alloc((size_t)(N_NODES + 1) * sizeof(int));
    int* bsum    = (int*)alloc(2048 * sizeof(int));
    const bool csr_ok = (off <= ws_size) && (nnz <= 11000000);  // CAP headroom

    const int spmm_blocks  = (N_NODES * 64 + 255) / 256;
    const int dense_blocks = (N_NODES + 63) / 64;

    if (csr_ok) {
        // ---- bucketed CSR build ----
        binhist_kernel<<<nch, 256, 0, stream>>>(rows, histT, nnz);
        {   // histT[nch][NB_B] -> histA[NB_B][nch]
            dim3 g((NB_B + 31) / 32, (nch + 31) / 32);
            transpose_kernel<<<g, 256, 0, stream>>>(histT, histA, nch, NB_B);
        }
        const int nsb = (n2 + SCAN_B - 1) / SCAN_B;       // <= 2048
        scan1_kernel<<<nsb, 256, 0, stream>>>(histA, bsum, n2);
        scan2_kernel<<<1, 256, 0, stream>>>(bsum, nsb);
        scan3_kernel<<<(n2 + 255) / 256, 256, 0, stream>>>(histA, bsum, n2);
        {   // histA[NB_B][nch] (scanned) -> curT[nch][NB_B]
            dim3 g((nch + 31) / 32, (NB_B + 31) / 32);
            transpose_kernel<<<g, 256, 0, stream>>>(histA, curT, NB_B, nch);
        }
        binscatter_kernel<<<nch, 512, 0, stream>>>(rows, cols, vals, curT, meta, nnz);
        bucketfinal_kernel<<<NB_B, 256, 0, stream>>>(histA, meta, row_ptr, nnz, nch);

        // emb -> out[:,0:64] + fp8 gather table (hist region now dead)
        emb_prep_kernel<<<(N_NODES * 16 + 255) / 256, 256, 0, stream>>>(
            (const float4*)emb, (unsigned*)emb_f8, (float4*)out);

        // ---- layer 0 ----
        spmm_csr_f8_kernel<<<spmm_blocks, 256, 0, stream>>>(
            (const uint2*)emb_f8, row_ptr, meta, side);
        dense_mfma_kernel<true, true><<<dense_blocks, 256, 0, stream>>>(
            emb, nullptr, side, gc_w0, gc_b0, bi_w0, bi_b0,
            ego1_b, ego1_f8, out, DIM);           // ego1_f8 overwrites emb_f8 (dead)

        // ---- layer 1 ----
        spmm_csr_f8_kernel<<<spmm_blocks, 256, 0, stream>>>(
            (const uint2*)ego1_f8, row_ptr, meta, side);
        dense_mfma_kernel<false, false><<<dense_blocks, 256, 0, stream>>>(
            nullptr, ego1_b, side, gc_w1, gc_b1, bi_w1, bi_b1,
            nullptr, nullptr, out, 2 * DIM);
    } else {
        // ---- fallback: atomic SpMM + fp32 dense ----
        float* ego1 = (float*)meta;   // nnz*8 B >= N*DIM*4 B
        const size_t side_bytes = (size_t)N_NODES * DIM * sizeof(float);
        const long long total = (long long)nnz * DIM;
        const int ab = (int)((total + 255) / 256);
        const int db = (N_NODES + 31) / 32;
        hipMemsetAsync(side, 0, side_bytes, stream);
        spmm_atomic_kernel<<<ab, 256, 0, stream>>>(emb, rows, cols, vals, side, nnz);
        dense_norm_kernel<true><<<db, 256, 0, stream>>>(
            emb, side, gc_w0, gc_b0, bi_w0, bi_b0, ego1, out, DIM);
        hipMemsetAsync(side, 0, side_bytes, stream);
        spmm_atomic_kernel<<<ab, 256, 0, stream>>>(ego1, rows, cols, vals, side, nnz);
        dense_norm_kernel<false><<<db, 256, 0, stream>>>(
            ego1, side, gc_w1, gc_b1, bi_w1, bi_b1, nullptr, out, 2 * DIM);
        copy_emb_kernel<<<(N_NODES * 16 + 255) / 256, 256, 0, stream>>>(
            (const float4*)emb, (float4*)out);
    }
}

// Round 12
// 798.338 us; speedup vs baseline: 1.0764x; 1.0764x over previous
//
#include <hip/hip_runtime.h>
#include <hip/hip_bf16.h>

// NGCF forward, MI355X. Sizes fixed by the problem.
constexpr int N_NODES = 300000;   // N_USERS + N_ITEMS
constexpr int DIM = 64;

// Bucketed CSR build parameters
constexpr int CHUNK  = 8192;            // edges per binning block
constexpr int B_ROWS = 256;             // rows per bucket (bucket = row >> 8)
constexpr int NB_B   = (N_NODES + B_ROWS - 1) / B_ROWS;   // 1172 buckets
constexpr int CAP    = 12288;           // max edges/bucket in bucketfinal LDS
constexpr int SCAN_B = 4096;            // elements per scan1 block (16/thread)
constexpr int COL_MASK = (1 << 19) - 1; // col < 2^19 (300000 < 524288)
constexpr float VAL_SCALE = 512.f;      // val*512 -> e4m3 normal range
constexpr float VAL_INV   = 1.f / 512.f;

typedef unsigned short ushort_t;
typedef unsigned char  uchar_t;
typedef __attribute__((ext_vector_type(8))) short bf16x8;
typedef __attribute__((ext_vector_type(4))) float f32x4;
typedef __attribute__((ext_vector_type(2))) float f32x2;
typedef __attribute__((ext_vector_type(4))) unsigned u32x4;

__device__ __forceinline__ float blo(unsigned u) { return __uint_as_float(u << 16); }
__device__ __forceinline__ float bhi(unsigned u) { return __uint_as_float(u & 0xffff0000u); }
__device__ __forceinline__ ushort_t f2b(float f) {            // fp32 -> bf16 (RNE)
    unsigned u = __float_as_uint(f);
    return (ushort_t)((u + 0x7fffu + ((u >> 16) & 1u)) >> 16);
}

// ---- fp8 e4m3fn helpers (OCP on gfx950). HI must be compile-time const. ----
template<bool HI>
__device__ __forceinline__ f32x2 f8cvt2(unsigned u) {
#if __has_builtin(__builtin_amdgcn_cvt_pk_f32_fp8)
    return __builtin_amdgcn_cvt_pk_f32_fp8((int)u, HI);
#else
    unsigned b0 = (u >> (HI ? 16 : 0)) & 0xffu, b1 = (u >> (HI ? 24 : 8)) & 0xffu;
    f32x2 r;
    r[0] = __uint_as_float(((b0 & 0x80u) << 24) | ((b0 & 0x7fu) << 20)) * 0x1p120f;
    r[1] = __uint_as_float(((b1 & 0x80u) << 24) | ((b1 & 0x7fu) << 20)) * 0x1p120f;
    return r;
#endif
}

__device__ __forceinline__ unsigned sw_e4m3(float f) {        // fallback encode (RNE)
    unsigned u = __float_as_uint(f);
    unsigned s = (u >> 24) & 0x80u;
    float a = fabsf(f);
    if (a >= 464.f) return s | 0x7eu;
    int E = (int)((u >> 23) & 0xff) - 120;      // e4m3 biased exp
    if (E >= 1) {
        unsigned m = u & 0x7fffffu;
        unsigned keep = m >> 20;
        unsigned rest = m & 0xfffffu;
        keep += (rest > 0x80000u || (rest == 0x80000u && (keep & 1u))) ? 1u : 0u;
        if (keep == 8u) { keep = 0u; E += 1; }
        if (E > 15 || (E == 15 && keep > 6u)) return s | 0x7eu;
        return s | ((unsigned)E << 3) | keep;
    } else {
        int q = (int)rintf(a * 512.f);
        if (q > 7) return s | 0x08u;
        return s | (unsigned)q;
    }
}

__device__ __forceinline__ unsigned f8pack4(float a, float b, float c, float d) {
#if __has_builtin(__builtin_amdgcn_cvt_pk_fp8_f32)
    int r = 0;
    r = __builtin_amdgcn_cvt_pk_fp8_f32(a, b, r, false);
    r = __builtin_amdgcn_cvt_pk_fp8_f32(c, d, r, true);
    return (unsigned)r;
#else
    return sw_e4m3(a) | (sw_e4m3(b) << 8) | (sw_e4m3(c) << 16) | (sw_e4m3(d) << 24);
#endif
}

__device__ __forceinline__ unsigned f8pack1(float a) {
#if __has_builtin(__builtin_amdgcn_cvt_pk_fp8_f32)
    int r = __builtin_amdgcn_cvt_pk_fp8_f32(a, 0.f, 0, false);
    return (unsigned)(r & 0xff);
#else
    return sw_e4m3(a);
#endif
}

// ---------------------------------------------------------------------------
// k1: per-chunk bucket histogram. histT[chunk][b] (coalesced write).
// ---------------------------------------------------------------------------
__global__ __launch_bounds__(256) void binhist_kernel(
    const int* __restrict__ rows, int* __restrict__ histT, int nnz)
{
    __shared__ int cnt[NB_B];
    for (int i = threadIdx.x; i < NB_B; i += 256) cnt[i] = 0;
    __syncthreads();
    int base = blockIdx.x * CHUNK;
#pragma unroll
    for (int k = 0; k < CHUNK / 256; ++k) {
        int e = base + k * 256 + threadIdx.x;
        if (e < nnz) atomicAdd(&cnt[rows[e] >> 8], 1);
    }
    __syncthreads();
    for (int b = threadIdx.x; b < NB_B; b += 256)
        histT[(size_t)blockIdx.x * NB_B + b] = cnt[b];
}

// 32x32 tiled transpose: in[R][C] -> out[C][R]
__global__ __launch_bounds__(256) void transpose_kernel(
    const int* __restrict__ in, int* __restrict__ out, int R, int C)
{
    __shared__ int tile[32][33];
    int c0 = blockIdx.x * 32, r0 = blockIdx.y * 32;
    int tx = threadIdx.x & 31, ty = threadIdx.x >> 5;
#pragma unroll
    for (int k = 0; k < 4; ++k) {
        int r = r0 + ty + k * 8, c = c0 + tx;
        if (r < R && c < C) tile[ty + k * 8][tx] = in[(size_t)r * C + c];
    }
    __syncthreads();
#pragma unroll
    for (int k = 0; k < 4; ++k) {
        int c = c0 + ty + k * 8, r = r0 + tx;
        if (c < C && r < R) out[(size_t)c * R + r] = tile[tx][ty + k * 8];
    }
}

// ---------------------------------------------------------------------------
// Exclusive scan over n elements (in place).
// ---------------------------------------------------------------------------
__global__ __launch_bounds__(256) void scan1_kernel(
    int* __restrict__ a, int* __restrict__ bsum, int n)
{
    __shared__ int tsum[256];
    int base = blockIdx.x * SCAN_B;
    int v[16];
    int s = 0;
#pragma unroll
    for (int k = 0; k < 16; ++k) {
        int i = base + threadIdx.x * 16 + k;
        v[k] = (i < n) ? a[i] : 0;
        s += v[k];
    }
    tsum[threadIdx.x] = s;
    __syncthreads();
    for (int off = 1; off < 256; off <<= 1) {
        int u = (threadIdx.x >= off) ? tsum[threadIdx.x - off] : 0;
        __syncthreads();
        tsum[threadIdx.x] += u;
        __syncthreads();
    }
    int excl = (threadIdx.x == 0) ? 0 : tsum[threadIdx.x - 1];
#pragma unroll
    for (int k = 0; k < 16; ++k) {
        int i = base + threadIdx.x * 16 + k;
        if (i < n) a[i] = excl;
        excl += v[k];
    }
    if (threadIdx.x == 255) bsum[blockIdx.x] = tsum[255];
}

__global__ __launch_bounds__(256) void scan2_kernel(int* bsum, int nb)   // nb <= 2048
{
    __shared__ int tsum[256];
    int v[8];
    int s = 0;
#pragma unroll
    for (int k = 0; k < 8; ++k) {
        int i = threadIdx.x * 8 + k;
        v[k] = (i < nb) ? bsum[i] : 0;
        s += v[k];
    }
    tsum[threadIdx.x] = s;
    __syncthreads();
    for (int off = 1; off < 256; off <<= 1) {
        int u = (threadIdx.x >= off) ? tsum[threadIdx.x - off] : 0;
        __syncthreads();
        tsum[threadIdx.x] += u;
        __syncthreads();
    }
    int excl = (threadIdx.x == 0) ? 0 : tsum[threadIdx.x - 1];
#pragma unroll
    for (int k = 0; k < 8; ++k) {
        int i = threadIdx.x * 8 + k;
        if (i < nb) bsum[i] = excl;
        excl += v[k];
    }
}

__global__ __launch_bounds__(256) void scan3_kernel(
    int* __restrict__ a, const int* __restrict__ bsum, int n)
{
    int i = blockIdx.x * 256 + threadIdx.x;
    if (i < n) a[i] += bsum[i >> 12];    // SCAN_B = 4096
}

// ---------------------------------------------------------------------------
// k5: binned scatter — LDS counting-sort of the chunk, then ordered flush.
// Payload packed: x = col | (local_row << 19), y = val bits.
// ---------------------------------------------------------------------------
__global__ __launch_bounds__(512) void binscatter_kernel(
    const int* __restrict__ rows, const int* __restrict__ cols,
    const float* __restrict__ vals, const int* __restrict__ curT,
    int2* __restrict__ meta, int nnz)
{
    __shared__ int2 cv[CHUNK];      // 64 KB  sorted payload
    __shared__ int  dst[CHUNK];     // 32 KB  global destination per slot
    __shared__ int  cnt[NB_B];      // hist, then per-bucket cursor
    __shared__ int  loc[NB_B];      // local exclusive offsets
    __shared__ int  gb[NB_B];       // global bases for this chunk
    __shared__ int  tsum[512];

    const int tid  = threadIdx.x;
    const int base = blockIdx.x * CHUNK;

    for (int b = tid; b < NB_B; b += 512) cnt[b] = 0;
    __syncthreads();

    int rb[16], pk[16], vb[16];
#pragma unroll
    for (int k = 0; k < 16; ++k) {
        int e = base + k * 512 + tid;
        if (e < nnz) {
            int r = rows[e];
            rb[k] = r >> 8;
            pk[k] = cols[e] | ((r & 255) << 19);
            vb[k] = __float_as_int(vals[e]);
            atomicAdd(&cnt[rb[k]], 1);
        } else rb[k] = -1;
    }
    __syncthreads();

    int i0 = tid * 3;
    int c0 = 0, c1 = 0, c2 = 0, s = 0;
    if (i0     < NB_B) { c0 = cnt[i0];     s += c0; }
    if (i0 + 1 < NB_B) { c1 = cnt[i0 + 1]; s += c1; }
    if (i0 + 2 < NB_B) { c2 = cnt[i0 + 2]; s += c2; }
    tsum[tid] = s;
    __syncthreads();
    for (int off = 1; off < 512; off <<= 1) {
        int u = (tid >= off) ? tsum[tid - off] : 0;
        __syncthreads();
        tsum[tid] += u;
        __syncthreads();
    }
    int ex = (tid == 0) ? 0 : tsum[tid - 1];
    if (i0     < NB_B) { loc[i0]     = ex; ex += c0; }
    if (i0 + 1 < NB_B) { loc[i0 + 1] = ex; ex += c1; }
    if (i0 + 2 < NB_B) { loc[i0 + 2] = ex; ex += c2; }
    __syncthreads();

    for (int b = tid; b < NB_B; b += 512) {
        gb[b]  = curT[(size_t)blockIdx.x * NB_B + b];
        cnt[b] = 0;
    }
    __syncthreads();

#pragma unroll
    for (int k = 0; k < 16; ++k) {
        if (rb[k] >= 0) {
            int b   = rb[k];
            int off = atomicAdd(&cnt[b], 1);
            int p   = loc[b] + off;
            cv[p]   = make_int2(pk[k], vb[k]);
            dst[p]  = gb[b] + off;
        }
    }
    __syncthreads();

    int n = min(nnz - base, CHUNK);
    for (int i = tid; i < n; i += 512)
        meta[dst[i]] = cv[i];
}

// ---------------------------------------------------------------------------
// k6: per-bucket finalize. Builds row_ptr; emits row-sorted COMPACT records
// metaC[j] = col | fp8(val*512) << 19  (4 B/edge for the SpMM).
// ---------------------------------------------------------------------------
__global__ __launch_bounds__(256) void bucketfinal_kernel(
    const int* __restrict__ histS,      // [NB_B][nch] scanned (bucket-major)
    const int2* __restrict__ meta,
    unsigned* __restrict__ metaC,
    int* __restrict__ row_ptr, int nnz, int nch)
{
    __shared__ unsigned cc[CAP];        // 48 KB compact payload
    __shared__ uchar_t  lr[CAP];        // 12 KB local rows
    __shared__ int cnt[256], scn[256], cur[256];

    int b    = blockIdx.x;
    int base = histS[(size_t)b * nch];
    int end  = (b + 1 < gridDim.x) ? histS[(size_t)(b + 1) * nch] : nnz;
    int n    = min(end - base, CAP);

    cnt[threadIdx.x] = 0;
    __syncthreads();
    for (int i = threadIdx.x; i < n; i += 256) {
        int2 m = meta[base + i];
        int l = (m.x >> 19) & 255;
        unsigned v8 = f8pack1(__int_as_float(m.y) * VAL_SCALE);
        cc[i] = (unsigned)(m.x & COL_MASK) | (v8 << 19);
        lr[i] = (uchar_t)l;
        atomicAdd(&cnt[l], 1);
    }
    __syncthreads();
    int v = cnt[threadIdx.x];
    scn[threadIdx.x] = v;
    __syncthreads();
    for (int off = 1; off < 256; off <<= 1) {
        int u = (threadIdx.x >= off) ? scn[threadIdx.x - off] : 0;
        __syncthreads();
        scn[threadIdx.x] += u;
        __syncthreads();
    }
    int excl = scn[threadIdx.x] - v;

    int r0 = b * B_ROWS;
    int nr = min(B_ROWS, N_NODES - r0);
    if (threadIdx.x < nr) row_ptr[r0 + threadIdx.x] = base + excl;
    if (b == gridDim.x - 1 && threadIdx.x == 0) row_ptr[N_NODES] = nnz;

    cur[threadIdx.x] = excl;
    __syncthreads();
    for (int i = threadIdx.x; i < n; i += 256) {
        int d = atomicAdd(&cur[lr[i]], 1);
        metaC[base + d] = cc[i];
    }
}

// ---------------------------------------------------------------------------
// emb prep: out[:,0:64] = emb AND fp8 gather table, one pass over emb.
// ---------------------------------------------------------------------------
__global__ __launch_bounds__(256) void emb_prep_kernel(
    const float4* __restrict__ emb, unsigned* __restrict__ tblF8,
    float* __restrict__ out)
{
    int i = blockIdx.x * 256 + threadIdx.x;
    if (i >= N_NODES * 16) return;
    float4 x = emb[i];
    int n = i >> 4, j = i & 15;
    f32x4 xv = {x.x, x.y, x.z, x.w};
    __builtin_nontemporal_store(xv, (f32x4*)(out + (size_t)n * 192 + j * 4));
    tblF8[i] = f8pack4(x.x, x.y, x.z, x.w);
}

// ---------------------------------------------------------------------------
// CSR SpMM, fp8 table + 4B compact edge records: one wave per row,
// 8 edge slots x 8 dim-eighths. fp32 accumulate; bf16 side store (1/512
// val scale folded into the store).
// ---------------------------------------------------------------------------
__global__ __launch_bounds__(256) void spmm_csr_f8_kernel(
    const uint2* __restrict__ tbl8,       // fp8 rows of 64 B
    const int*   __restrict__ row_ptr,
    const unsigned* __restrict__ metaC,   // col | v8<<19
    ushort_t*    __restrict__ side_b16)   // bf16 [N][64]
{
    int wid = (blockIdx.x * 256 + threadIdx.x) >> 6;
    if (wid >= N_NODES) return;
    int lane = threadIdx.x & 63;
    int g = lane >> 3;
    int q = lane & 7;

    int start = row_ptr[wid];
    int end   = row_ptr[wid + 1];

    float acc[8];
#pragma unroll
    for (int i = 0; i < 8; ++i) acc[i] = 0.f;

    for (int j = start + g; j < end; j += 8) {
        unsigned mc = metaC[j];
        float v = f8cvt2<false>(mc >> 19)[0];    // val*512
        uint2 x = tbl8[(size_t)(mc & COL_MASK) * 8 + q];
        f32x2 f0 = f8cvt2<false>(x.x), f1 = f8cvt2<true>(x.x);
        f32x2 f2 = f8cvt2<false>(x.y), f3 = f8cvt2<true>(x.y);
        acc[0] += v * f0[0]; acc[1] += v * f0[1];
        acc[2] += v * f1[0]; acc[3] += v * f1[1];
        acc[4] += v * f2[0]; acc[5] += v * f2[1];
        acc[6] += v * f3[0]; acc[7] += v * f3[1];
    }
#pragma unroll
    for (int off = 8; off <= 32; off <<= 1) {
#pragma unroll
        for (int i = 0; i < 8; ++i) acc[i] += __shfl_xor(acc[i], off);
    }
    if (g == 0) {
        u32x4 pk;
        pk.x = ((unsigned)f2b(acc[1] * VAL_INV) << 16) | f2b(acc[0] * VAL_INV);
        pk.y = ((unsigned)f2b(acc[3] * VAL_INV) << 16) | f2b(acc[2] * VAL_INV);
        pk.z = ((unsigned)f2b(acc[5] * VAL_INV) << 16) | f2b(acc[4] * VAL_INV);
        pk.w = ((unsigned)f2b(acc[7] * VAL_INV) << 16) | f2b(acc[6] * VAL_INV);
        __builtin_nontemporal_store(pk, (u32x4*)(side_b16 + (size_t)wid * DIM + q * 8));
    }
}

// ---------------------------------------------------------------------------
// MFMA dense layer: y = leaky(s@gw.T + gb + p@bw.T + bb), s=side+e, p=side*e.
// side is bf16. Layer 0 reads ego fp32 (emb); layer 1 reads bf16 ego table.
// Layer 0 epilogue writes next-layer tables: bf16 (dense) + fp8 (gather).
// ---------------------------------------------------------------------------
template<bool EGO_F32, bool WRITE_TBL>
__global__ __launch_bounds__(256) void dense_mfma_kernel(
    const float*   __restrict__ ego_f32,    // EGO_F32
    const ushort_t* __restrict__ ego_b16,   // !EGO_F32
    const ushort_t* __restrict__ side_b16,
    const float* __restrict__ gw, const float* __restrict__ gb,
    const float* __restrict__ bw, const float* __restrict__ bb,
    ushort_t* __restrict__ tblb_out,        // bf16 ego out (layer 0)
    uchar_t*  __restrict__ tblf8_out,       // fp8 ego out (layer 0)
    float* __restrict__ out, int out_col)
{
    __shared__ ushort_t s_lds[64][72];      // 9 KB (pad 8 bf16 = 16 B)
    __shared__ ushort_t p_lds[64][72];      // 9 KB

    const int tid  = threadIdx.x;
    const int lane = tid & 63;
    const int wv   = tid >> 6;
    const int lrow = lane & 15;
    const int kgrp = lane >> 4;

    // B-fragments (weights) + bias, loaded once
    bf16x8 wgf[4][2], wbf[4][2];
    float  biasv[4];
#pragma unroll
    for (int t = 0; t < 4; ++t) {
        int o = 16 * t + lrow;
#pragma unroll
        for (int h = 0; h < 2; ++h) {
            const float* pg = gw + (size_t)o * DIM + 32 * h + 8 * kgrp;
            const float* pb = bw + (size_t)o * DIM + 32 * h + 8 * kgrp;
            ushort_t tg[8], tb[8];
#pragma unroll
            for (int i = 0; i < 8; ++i) { tg[i] = f2b(pg[i]); tb[i] = f2b(pb[i]); }
            wgf[t][h] = *(const bf16x8*)tg;
            wbf[t][h] = *(const bf16x8*)tb;
        }
        biasv[t] = gb[o] + bb[o];
    }

    for (int tile0 = blockIdx.x * 64; tile0 < N_NODES; tile0 += gridDim.x * 64) {
        int nmax = min(64, N_NODES - tile0);
        __syncthreads();
        // ---- stage s,p (bf16) for 64 nodes: thread = (row, dim-quarter) ----
        {
            int r  = tid >> 2;
            int d0 = (tid & 3) * 16;
            if (r < nmax) {
                const uint4* sp = (const uint4*)(side_b16 + (size_t)(tile0 + r) * DIM + d0);
                uint4 sb0 = sp[0], sb1 = sp[1];
                float sv[16] = { blo(sb0.x), bhi(sb0.x), blo(sb0.y), bhi(sb0.y),
                                 blo(sb0.z), bhi(sb0.z), blo(sb0.w), bhi(sb0.w),
                                 blo(sb1.x), bhi(sb1.x), blo(sb1.y), bhi(sb1.y),
                                 blo(sb1.z), bhi(sb1.z), blo(sb1.w), bhi(sb1.w) };
                float ev[16];
                if (EGO_F32) {
                    const float4* ep = (const float4*)(ego_f32 + (size_t)(tile0 + r) * DIM + d0);
                    float4 e0 = ep[0], e1 = ep[1], e2 = ep[2], e3 = ep[3];
                    float tmp[16] = { e0.x, e0.y, e0.z, e0.w, e1.x, e1.y, e1.z, e1.w,
                                      e2.x, e2.y, e2.z, e2.w, e3.x, e3.y, e3.z, e3.w };
#pragma unroll
                    for (int i = 0; i < 16; ++i) ev[i] = tmp[i];
                } else {
                    const uint4* ep = (const uint4*)(ego_b16 + (size_t)(tile0 + r) * DIM + d0);
                    uint4 e0 = ep[0], e1 = ep[1];
                    float tmp[16] = { blo(e0.x), bhi(e0.x), blo(e0.y), bhi(e0.y),
                                      blo(e0.z), bhi(e0.z), blo(e0.w), bhi(e0.w),
                                      blo(e1.x), bhi(e1.x), blo(e1.y), bhi(e1.y),
                                      blo(e1.z), bhi(e1.z), blo(e1.w), bhi(e1.w) };
#pragma unroll
                    for (int i = 0; i < 16; ++i) ev[i] = tmp[i];
                }
                unsigned spk[8], ppk[8];
#pragma unroll
                for (int i = 0; i < 8; ++i) {
                    float a  = sv[2*i]   + ev[2*i];
                    float b2 = sv[2*i+1] + ev[2*i+1];
                    float c  = sv[2*i]   * ev[2*i];
                    float d  = sv[2*i+1] * ev[2*i+1];
                    spk[i] = ((unsigned)f2b(b2) << 16) | f2b(a);
                    ppk[i] = ((unsigned)f2b(d)  << 16) | f2b(c);
                }
                *(uint4*)&s_lds[r][d0]     = make_uint4(spk[0], spk[1], spk[2], spk[3]);
                *(uint4*)&s_lds[r][d0 + 8] = make_uint4(spk[4], spk[5], spk[6], spk[7]);
                *(uint4*)&p_lds[r][d0]     = make_uint4(ppk[0], ppk[1], ppk[2], ppk[3]);
                *(uint4*)&p_lds[r][d0 + 8] = make_uint4(ppk[4], ppk[5], ppk[6], ppk[7]);
            }
        }
        __syncthreads();

        // ---- compute: wave wv owns nodes tile0 + wv*16 .. +15 ----
        const int arow = wv * 16 + lrow;
        bf16x8 sf[2], pf[2];
        sf[0] = *(const bf16x8*)&s_lds[arow][8 * kgrp];
        sf[1] = *(const bf16x8*)&s_lds[arow][32 + 8 * kgrp];
        pf[0] = *(const bf16x8*)&p_lds[arow][8 * kgrp];
        pf[1] = *(const bf16x8*)&p_lds[arow][32 + 8 * kgrp];

        f32x4 acc[4];
#pragma unroll
        for (int t = 0; t < 4; ++t)
            acc[t] = (f32x4){biasv[t], biasv[t], biasv[t], biasv[t]};

#pragma unroll
        for (int h = 0; h < 2; ++h) {
#pragma unroll
            for (int t = 0; t < 4; ++t) {
                acc[t] = __builtin_amdgcn_mfma_f32_16x16x32_bf16(sf[h], wgf[t][h], acc[t], 0, 0, 0);
                acc[t] = __builtin_amdgcn_mfma_f32_16x16x32_bf16(pf[h], wbf[t][h], acc[t], 0, 0, 0);
            }
        }

        // ---- epilogue: leaky, row-norm (16-lane group reduce), stores ----
        float y[4][4];
        float ssr[4] = {0.f, 0.f, 0.f, 0.f};
#pragma unroll
        for (int t = 0; t < 4; ++t)
#pragma unroll
            for (int rg = 0; rg < 4; ++rg) {
                float v = acc[t][rg];
                v = v > 0.f ? v : 0.2f * v;
                y[t][rg] = v;
                ssr[rg] += v * v;
            }
#pragma unroll
        for (int off = 1; off <= 8; off <<= 1)
#pragma unroll
            for (int rg = 0; rg < 4; ++rg)
                ssr[rg] += __shfl_xor(ssr[rg], off);

#pragma unroll
        for (int rg = 0; rg < 4; ++rg) {
            int node = tile0 + wv * 16 + kgrp * 4 + rg;
            if (node < N_NODES) {
                float inv = 1.0f / fmaxf(sqrtf(ssr[rg]), 1e-12f);
                float* orow = out + (size_t)node * 192 + out_col;
#pragma unroll
                for (int t = 0; t < 4; ++t)
                    orow[t * 16 + lrow] = y[t][rg] * inv;
                if (WRITE_TBL) {
#pragma unroll
                    for (int t = 0; t < 4; ++t) {
                        tblb_out[(size_t)node * DIM + t * 16 + lrow] = f2b(y[t][rg]);
                        tblf8_out[(size_t)node * DIM + t * 16 + lrow] = (uchar_t)f8pack1(y[t][rg]);
                    }
                }
            }
        }
    }
}

// ---------------------------------------------------------------------------
// Fallback path (ws too small): atomic SpMM + fp32 dense.
// ---------------------------------------------------------------------------
__global__ __launch_bounds__(256) void spmm_atomic_kernel(
    const float* __restrict__ ego,
    const int*   __restrict__ rows,
    const int*   __restrict__ cols,
    const float* __restrict__ vals,
    float*       __restrict__ side,
    int nnz)
{
    long long i = (long long)blockIdx.x * blockDim.x + threadIdx.x;
    long long total = (long long)nnz * DIM;
    if (i >= total) return;
    int e = (int)(i >> 6);
    int d = (int)(i & 63);
    atomicAdd(side + ((size_t)rows[e] * DIM + d), vals[e] * ego[(size_t)cols[e] * DIM + d]);
}

template<bool WRITE_F32>
__global__ __launch_bounds__(256) void dense_norm_kernel(
    const float* __restrict__ ego_in,
    const float* __restrict__ side,
    const float* __restrict__ gw, const float* __restrict__ gb,
    const float* __restrict__ bw, const float* __restrict__ bb,
    float* __restrict__ ego_out,
    float* __restrict__ out, int out_col)
{
    __shared__ float s_lds[32][DIM];
    __shared__ float p_lds[32][DIM];

    const int o  = threadIdx.x & 63;
    const int wv = threadIdx.x >> 6;

    float w0[DIM], w1[DIM];
#pragma unroll
    for (int k4 = 0; k4 < DIM / 4; ++k4) {
        float4 a = *(const float4*)(gw + (size_t)o * DIM + k4 * 4);
        float4 b = *(const float4*)(bw + (size_t)o * DIM + k4 * 4);
        w0[4*k4+0] = a.x; w0[4*k4+1] = a.y; w0[4*k4+2] = a.z; w0[4*k4+3] = a.w;
        w1[4*k4+0] = b.x; w1[4*k4+1] = b.y; w1[4*k4+2] = b.z; w1[4*k4+3] = b.w;
    }
    const float bias = gb[o] + bb[o];

    for (int tile = blockIdx.x * 32; tile < N_NODES; tile += gridDim.x * 32) {
        int nmax = min(32, N_NODES - tile);
        __syncthreads();
        const float4* sd4 = (const float4*)side + (size_t)tile * 16;
        const float4* eg4 = (const float4*)ego_in + (size_t)tile * 16;
        float4* s4 = (float4*)&s_lds[0][0];
        float4* p4 = (float4*)&p_lds[0][0];
        for (int i = threadIdx.x; i < nmax * 16; i += 256) {
            float4 e = eg4[i], s = sd4[i];
            s4[i] = make_float4(s.x+e.x, s.y+e.y, s.z+e.z, s.w+e.w);
            p4[i] = make_float4(s.x*e.x, s.y*e.y, s.z*e.z, s.w*e.w);
        }
        __syncthreads();
        for (int n = wv; n < nmax; n += 4) {
            const float4* srow = (const float4*)&s_lds[n][0];
            const float4* prow = (const float4*)&p_lds[n][0];
            float a0 = bias, a1 = 0.f, a2 = 0.f, a3 = 0.f;
#pragma unroll
            for (int k4 = 0; k4 < 16; ++k4) {
                float4 sk = srow[k4];
                float4 pk = prow[k4];
                a0 = fmaf(sk.x, w0[4*k4+0], a0); a1 = fmaf(pk.x, w1[4*k4+0], a1);
                a2 = fmaf(sk.y, w0[4*k4+1], a2); a3 = fmaf(pk.y, w1[4*k4+1], a3);
                a0 = fmaf(sk.z, w0[4*k4+2], a0); a1 = fmaf(pk.z, w1[4*k4+2], a1);
                a2 = fmaf(sk.w, w0[4*k4+3], a2); a3 = fmaf(pk.w, w1[4*k4+3], a3);
            }
            float acc = (a0 + a1) + (a2 + a3);
            float y = acc > 0.f ? acc : 0.2f * acc;
            size_t node = (size_t)(tile + n);
            if (WRITE_F32) ego_out[node * DIM + o] = y;
            float ss = y * y;
#pragma unroll
            for (int off = 32; off > 0; off >>= 1)
                ss += __shfl_xor(ss, off);
            float inv = 1.0f / fmaxf(sqrtf(ss), 1e-12f);
            out[node * 192 + out_col + o] = y * inv;
        }
    }
}

__global__ __launch_bounds__(256) void copy_emb_kernel(
    const float4* __restrict__ emb, float4* __restrict__ out)
{
    int i = blockIdx.x * blockDim.x + threadIdx.x;
    if (i >= N_NODES * 16) return;
    int n = i >> 4, j = i & 15;
    out[(size_t)n * 48 + j] = emb[i];
}

extern "C" void kernel_launch(void* const* d_in, const int* in_sizes, int n_in,
                              void* d_out, int out_size, void* d_ws, size_t ws_size,
                              hipStream_t stream)
{
    const float* emb   = (const float*)d_in[0];
    const float* gc_w0 = (const float*)d_in[1];
    const float* gc_b0 = (const float*)d_in[2];
    const float* bi_w0 = (const float*)d_in[3];
    const float* bi_b0 = (const float*)d_in[4];
    const float* gc_w1 = (const float*)d_in[5];
    const float* gc_b1 = (const float*)d_in[6];
    const float* bi_w1 = (const float*)d_in[7];
    const float* bi_b1 = (const float*)d_in[8];
    const int*   rows  = (const int*)d_in[9];
    const int*   cols  = (const int*)d_in[10];
    const float* vals  = (const float*)d_in[11];
    const int    nnz   = in_sizes[9];

    float* out = (float*)d_out;

    const int nch = (nnz + CHUNK - 1) / CHUNK;            // chunks
    const int n2  = NB_B * nch;                           // hist entries
    const size_t hist_al = (((size_t)n2 * sizeof(int)) + 63) & ~size_t(63);
    const size_t tbl_al  = (((size_t)N_NODES * DIM) + 63) & ~size_t(63);  // fp8 table bytes

    // ---- workspace layout ----
    char* ws = (char*)d_ws;
    size_t off = 0;
    auto alloc = [&](size_t bytes) { char* p = ws + off; off += (bytes + 63) & ~size_t(63); return p; };
    // sideRegion: fallback = fp32 side (N*DIM*4). CSR path: low half bf16 side,
    // high half metaC (nnz*4 <= N*DIM*2 guarded below).
    char* sideRegion = alloc((size_t)N_NODES * DIM * sizeof(float));
    float*    side_f32 = (float*)sideRegion;
    ushort_t* side_b16 = (ushort_t*)sideRegion;
    unsigned* metaC    = (unsigned*)(sideRegion + (size_t)N_NODES * DIM * sizeof(ushort_t));
    ushort_t* ego1_b = (ushort_t*)alloc((size_t)N_NODES * DIM * sizeof(ushort_t));
    int2* meta = (int2*)alloc((size_t)nnz * sizeof(int2));
    // Union region: build-phase {histT, histA}; post-build {emb_f8 / ego1_f8 (time-shared)}
    size_t u_build = 2 * hist_al;
    char* U = alloc(u_build > tbl_al ? u_build : tbl_al);
    int* histT = (int*)U;
    int* histA = (int*)(U + hist_al);
    int* curT  = histT;                                   // reuse after transpose 1
    uchar_t* emb_f8  = (uchar_t*)U;                       // alive: emb_prep..spmm0
    uchar_t* ego1_f8 = (uchar_t*)U;                       // alive: dense0..spmm1
    int* row_ptr = (int*)alloc((size_t)(N_NODES + 1) * sizeof(int));
    int* bsum    = (int*)alloc(2048 * sizeof(int));
    const bool csr_ok = (off <= ws_size) && (nnz <= 11000000) &&
                        ((size_t)nnz * 4 <= (size_t)N_NODES * DIM * 2);  // metaC fits

    const int spmm_blocks  = (N_NODES * 64 + 255) / 256;
    const int dense_blocks = (N_NODES + 63) / 64;

    if (csr_ok) {
        // ---- bucketed CSR build ----
        binhist_kernel<<<nch, 256, 0, stream>>>(rows, histT, nnz);
        {   // histT[nch][NB_B] -> histA[NB_B][nch]
            dim3 g((NB_B + 31) / 32, (nch + 31) / 32);
            transpose_kernel<<<g, 256, 0, stream>>>(histT, histA, nch, NB_B);
        }
        const int nsb = (n2 + SCAN_B - 1) / SCAN_B;       // <= 2048
        scan1_kernel<<<nsb, 256, 0, stream>>>(histA, bsum, n2);
        scan2_kernel<<<1, 256, 0, stream>>>(bsum, nsb);
        scan3_kernel<<<(n2 + 255) / 256, 256, 0, stream>>>(histA, bsum, n2);
        {   // histA[NB_B][nch] (scanned) -> curT[nch][NB_B]
            dim3 g((nch + 31) / 32, (NB_B + 31) / 32);
            transpose_kernel<<<g, 256, 0, stream>>>(histA, curT, NB_B, nch);
        }
        binscatter_kernel<<<nch, 512, 0, stream>>>(rows, cols, vals, curT, meta, nnz);
        bucketfinal_kernel<<<NB_B, 256, 0, stream>>>(histA, meta, metaC, row_ptr, nnz, nch);

        // emb -> out[:,0:64] + fp8 gather table (hist region now dead)
        emb_prep_kernel<<<(N_NODES * 16 + 255) / 256, 256, 0, stream>>>(
            (const float4*)emb, (unsigned*)emb_f8, out);

        // ---- layer 0 ----
        spmm_csr_f8_kernel<<<spmm_blocks, 256, 0, stream>>>(
            (const uint2*)emb_f8, row_ptr, metaC, side_b16);
        dense_mfma_kernel<true, true><<<dense_blocks, 256, 0, stream>>>(
            emb, nullptr, side_b16, gc_w0, gc_b0, bi_w0, bi_b0,
            ego1_b, ego1_f8, out, DIM);           // ego1_f8 overwrites emb_f8 (dead)

        // ---- layer 1 ----
        spmm_csr_f8_kernel<<<spmm_blocks, 256, 0, stream>>>(
            (const uint2*)ego1_f8, row_ptr, metaC, side_b16);
        dense_mfma_kernel<false, false><<<dense_blocks, 256, 0, stream>>>(
            nullptr, ego1_b, side_b16, gc_w1, gc_b1, bi_w1, bi_b1,
            nullptr, nullptr, out, 2 * DIM);
    } else {
        // ---- fallback: atomic SpMM + fp32 dense ----
        float* ego1 = (float*)meta;   // nnz*8 B >= N*DIM*4 B
        const size_t side_bytes = (size_t)N_NODES * DIM * sizeof(float);
        const long long total = (long long)nnz * DIM;
        const int ab = (int)((total + 255) / 256);
        const int db = (N_NODES + 31) / 32;
        hipMemsetAsync(side_f32, 0, side_bytes, stream);
        spmm_atomic_kernel<<<ab, 256, 0, stream>>>(emb, rows, cols, vals, side_f32, nnz);
        dense_norm_kernel<true><<<db, 256, 0, stream>>>(
            emb, side_f32, gc_w0, gc_b0, bi_w0, bi_b0, ego1, out, DIM);
        hipMemsetAsync(side_f32, 0, side_bytes, stream);
        spmm_atomic_kernel<<<ab, 256, 0, stream>>>(ego1, rows, cols, vals, side_f32, nnz);
        dense_norm_kernel<false><<<db, 256, 0, stream>>>(
            ego1, side_f32, gc_w1, gc_b1, bi_w1, bi_b1, nullptr, out, 2 * DIM);
        copy_emb_kernel<<<(N_NODES * 16 + 255) / 256, 256, 0, stream>>>(
            (const float4*)emb, (float4*)out);
    }
}

// Round 13
// 700.538 us; speedup vs baseline: 1.2267x; 1.1396x over previous
//
#include <hip/hip_runtime.h>
#include <hip/hip_bf16.h>

// NGCF forward, MI355X. Sizes fixed by the problem.
constexpr int N_NODES = 300000;   // N_USERS + N_ITEMS
constexpr int DIM = 64;

// Bucketed CSR build parameters
constexpr int CHUNK  = 8192;            // edges per binning block
constexpr int B_ROWS = 256;             // rows per bucket (bucket = row >> 8)
constexpr int NB_B   = (N_NODES + B_ROWS - 1) / B_ROWS;   // 1172 buckets
constexpr int CAP    = 12288;           // max edges/bucket in bucketfinal LDS
constexpr int SCAN_B = 4096;            // elements per scan1 block (16/thread)
constexpr int COL_MASK = (1 << 19) - 1; // col < 2^19 (300000 < 524288)
// Edge record: col[0:19) | val5[19:24) | local_row[24:32)
constexpr float VQ     = 992.0f;        // val in [0,1/32] -> 5-bit linear
constexpr float VQ_INV = 1.0f / 992.0f;

typedef unsigned short ushort_t;
typedef unsigned char  uchar_t;
typedef __attribute__((ext_vector_type(8))) short bf16x8;
typedef __attribute__((ext_vector_type(4))) float f32x4;
typedef __attribute__((ext_vector_type(2))) float f32x2;
typedef __attribute__((ext_vector_type(4))) unsigned u32x4;

__device__ __forceinline__ float blo(unsigned u) { return __uint_as_float(u << 16); }
__device__ __forceinline__ float bhi(unsigned u) { return __uint_as_float(u & 0xffff0000u); }
__device__ __forceinline__ ushort_t f2b(float f) {            // fp32 -> bf16 (RNE)
    unsigned u = __float_as_uint(f);
    return (ushort_t)((u + 0x7fffu + ((u >> 16) & 1u)) >> 16);
}

// ---- fp8 e4m3fn helpers (OCP on gfx950). HI must be compile-time const. ----
template<bool HI>
__device__ __forceinline__ f32x2 f8cvt2(unsigned u) {
#if __has_builtin(__builtin_amdgcn_cvt_pk_f32_fp8)
    return __builtin_amdgcn_cvt_pk_f32_fp8((int)u, HI);
#else
    unsigned b0 = (u >> (HI ? 16 : 0)) & 0xffu, b1 = (u >> (HI ? 24 : 8)) & 0xffu;
    f32x2 r;
    r[0] = __uint_as_float(((b0 & 0x80u) << 24) | ((b0 & 0x7fu) << 20)) * 0x1p120f;
    r[1] = __uint_as_float(((b1 & 0x80u) << 24) | ((b1 & 0x7fu) << 20)) * 0x1p120f;
    return r;
#endif
}

__device__ __forceinline__ unsigned sw_e4m3(float f) {        // fallback encode (RNE)
    unsigned u = __float_as_uint(f);
    unsigned s = (u >> 24) & 0x80u;
    float a = fabsf(f);
    if (a >= 464.f) return s | 0x7eu;
    int E = (int)((u >> 23) & 0xff) - 120;      // e4m3 biased exp
    if (E >= 1) {
        unsigned m = u & 0x7fffffu;
        unsigned keep = m >> 20;
        unsigned rest = m & 0xfffffu;
        keep += (rest > 0x80000u || (rest == 0x80000u && (keep & 1u))) ? 1u : 0u;
        if (keep == 8u) { keep = 0u; E += 1; }
        if (E > 15 || (E == 15 && keep > 6u)) return s | 0x7eu;
        return s | ((unsigned)E << 3) | keep;
    } else {
        int q = (int)rintf(a * 512.f);
        if (q > 7) return s | 0x08u;
        return s | (unsigned)q;
    }
}

__device__ __forceinline__ unsigned f8pack4(float a, float b, float c, float d) {
#if __has_builtin(__builtin_amdgcn_cvt_pk_fp8_f32)
    int r = 0;
    r = __builtin_amdgcn_cvt_pk_fp8_f32(a, b, r, false);
    r = __builtin_amdgcn_cvt_pk_fp8_f32(c, d, r, true);
    return (unsigned)r;
#else
    return sw_e4m3(a) | (sw_e4m3(b) << 8) | (sw_e4m3(c) << 16) | (sw_e4m3(d) << 24);
#endif
}

__device__ __forceinline__ unsigned f8pack1(float a) {
#if __has_builtin(__builtin_amdgcn_cvt_pk_fp8_f32)
    int r = __builtin_amdgcn_cvt_pk_fp8_f32(a, 0.f, 0, false);
    return (unsigned)(r & 0xff);
#else
    return sw_e4m3(a);
#endif
}

// ---------------------------------------------------------------------------
// k1: per-chunk bucket histogram. histT[chunk][b] (coalesced write).
// ---------------------------------------------------------------------------
__global__ __launch_bounds__(256) void binhist_kernel(
    const int* __restrict__ rows, int* __restrict__ histT, int nnz)
{
    __shared__ int cnt[NB_B];
    for (int i = threadIdx.x; i < NB_B; i += 256) cnt[i] = 0;
    __syncthreads();
    int base = blockIdx.x * CHUNK;
#pragma unroll
    for (int k = 0; k < CHUNK / 256; ++k) {
        int e = base + k * 256 + threadIdx.x;
        if (e < nnz) atomicAdd(&cnt[rows[e] >> 8], 1);
    }
    __syncthreads();
    for (int b = threadIdx.x; b < NB_B; b += 256)
        histT[(size_t)blockIdx.x * NB_B + b] = cnt[b];
}

// 32x32 tiled transpose: in[R][C] -> out[C][R]
__global__ __launch_bounds__(256) void transpose_kernel(
    const int* __restrict__ in, int* __restrict__ out, int R, int C)
{
    __shared__ int tile[32][33];
    int c0 = blockIdx.x * 32, r0 = blockIdx.y * 32;
    int tx = threadIdx.x & 31, ty = threadIdx.x >> 5;
#pragma unroll
    for (int k = 0; k < 4; ++k) {
        int r = r0 + ty + k * 8, c = c0 + tx;
        if (r < R && c < C) tile[ty + k * 8][tx] = in[(size_t)r * C + c];
    }
    __syncthreads();
#pragma unroll
    for (int k = 0; k < 4; ++k) {
        int c = c0 + ty + k * 8, r = r0 + tx;
        if (c < C && r < R) out[(size_t)c * R + r] = tile[tx][ty + k * 8];
    }
}

// ---------------------------------------------------------------------------
// Exclusive scan over n elements (in place).
// ---------------------------------------------------------------------------
__global__ __launch_bounds__(256) void scan1_kernel(
    int* __restrict__ a, int* __restrict__ bsum, int n)
{
    __shared__ int tsum[256];
    int base = blockIdx.x * SCAN_B;
    int v[16];
    int s = 0;
#pragma unroll
    for (int k = 0; k < 16; ++k) {
        int i = base + threadIdx.x * 16 + k;
        v[k] = (i < n) ? a[i] : 0;
        s += v[k];
    }
    tsum[threadIdx.x] = s;
    __syncthreads();
    for (int off = 1; off < 256; off <<= 1) {
        int u = (threadIdx.x >= off) ? tsum[threadIdx.x - off] : 0;
        __syncthreads();
        tsum[threadIdx.x] += u;
        __syncthreads();
    }
    int excl = (threadIdx.x == 0) ? 0 : tsum[threadIdx.x - 1];
#pragma unroll
    for (int k = 0; k < 16; ++k) {
        int i = base + threadIdx.x * 16 + k;
        if (i < n) a[i] = excl;
        excl += v[k];
    }
    if (threadIdx.x == 255) bsum[blockIdx.x] = tsum[255];
}

__global__ __launch_bounds__(256) void scan2_kernel(int* bsum, int nb)   // nb <= 2048
{
    __shared__ int tsum[256];
    int v[8];
    int s = 0;
#pragma unroll
    for (int k = 0; k < 8; ++k) {
        int i = threadIdx.x * 8 + k;
        v[k] = (i < nb) ? bsum[i] : 0;
        s += v[k];
    }
    tsum[threadIdx.x] = s;
    __syncthreads();
    for (int off = 1; off < 256; off <<= 1) {
        int u = (threadIdx.x >= off) ? tsum[threadIdx.x - off] : 0;
        __syncthreads();
        tsum[threadIdx.x] += u;
        __syncthreads();
    }
    int excl = (threadIdx.x == 0) ? 0 : tsum[threadIdx.x - 1];
#pragma unroll
    for (int k = 0; k < 8; ++k) {
        int i = threadIdx.x * 8 + k;
        if (i < nb) bsum[i] = excl;
        excl += v[k];
    }
}

__global__ __launch_bounds__(256) void scan3_kernel(
    int* __restrict__ a, const int* __restrict__ bsum, int n)
{
    int i = blockIdx.x * 256 + threadIdx.x;
    if (i < n) a[i] += bsum[i >> 12];    // SCAN_B = 4096
}

// ---------------------------------------------------------------------------
// k5: binned scatter — LDS counting-sort of the chunk, then ordered flush.
// Emits compact 4B records directly: col | val5<<19 | local_row<<24.
// ---------------------------------------------------------------------------
__global__ __launch_bounds__(512) void binscatter_kernel(
    const int* __restrict__ rows, const int* __restrict__ cols,
    const float* __restrict__ vals, const int* __restrict__ curT,
    unsigned* __restrict__ metaC, int nnz)
{
    __shared__ unsigned cv[CHUNK];      // 32 KB  sorted compact payload
    __shared__ ushort_t bidv[CHUNK];    // 16 KB  bucket id per slot
    __shared__ int  cnt[NB_B];          // hist, then per-bucket cursor
    __shared__ int  loc[NB_B];          // local exclusive offsets
    __shared__ int  gb[NB_B];           // global bases for this chunk
    __shared__ int  tsum[512];

    const int tid  = threadIdx.x;
    const int base = blockIdx.x * CHUNK;

    for (int b = tid; b < NB_B; b += 512) cnt[b] = 0;
    __syncthreads();

    int rb[16]; unsigned pk[16];
#pragma unroll
    for (int k = 0; k < 16; ++k) {
        int e = base + k * 512 + tid;
        if (e < nnz) {
            int r = rows[e];
            rb[k] = r >> 8;
            int v5 = (int)rintf(vals[e] * VQ);
            v5 = min(max(v5, 0), 31);
            pk[k] = (unsigned)cols[e] | ((unsigned)v5 << 19) | ((unsigned)(r & 255) << 24);
            atomicAdd(&cnt[rb[k]], 1);
        } else rb[k] = -1;
    }
    __syncthreads();

    int i0 = tid * 3;
    int c0 = 0, c1 = 0, c2 = 0, s = 0;
    if (i0     < NB_B) { c0 = cnt[i0];     s += c0; }
    if (i0 + 1 < NB_B) { c1 = cnt[i0 + 1]; s += c1; }
    if (i0 + 2 < NB_B) { c2 = cnt[i0 + 2]; s += c2; }
    tsum[tid] = s;
    __syncthreads();
    for (int off = 1; off < 512; off <<= 1) {
        int u = (tid >= off) ? tsum[tid - off] : 0;
        __syncthreads();
        tsum[tid] += u;
        __syncthreads();
    }
    int ex = (tid == 0) ? 0 : tsum[tid - 1];
    if (i0     < NB_B) { loc[i0]     = ex; ex += c0; }
    if (i0 + 1 < NB_B) { loc[i0 + 1] = ex; ex += c1; }
    if (i0 + 2 < NB_B) { loc[i0 + 2] = ex; ex += c2; }
    __syncthreads();

    for (int b = tid; b < NB_B; b += 512) {
        gb[b]  = curT[(size_t)blockIdx.x * NB_B + b];
        cnt[b] = 0;
    }
    __syncthreads();

#pragma unroll
    for (int k = 0; k < 16; ++k) {
        if (rb[k] >= 0) {
            int b   = rb[k];
            int off = atomicAdd(&cnt[b], 1);
            int p   = loc[b] + off;
            cv[p]   = pk[k];
            bidv[p] = (ushort_t)b;
        }
    }
    __syncthreads();

    // ordered flush: dst derived from bucket id (no dst array)
    int n = min(nnz - base, CHUNK);
    for (int i = tid; i < n; i += 512) {
        int b = bidv[i];
        metaC[gb[b] + (i - loc[b])] = cv[i];
    }
}

// ---------------------------------------------------------------------------
// k6: per-bucket finalize. Builds row_ptr; permutes 4B records in place
// into row order (local row = rec >> 24).
// ---------------------------------------------------------------------------
__global__ __launch_bounds__(256) void bucketfinal_kernel(
    const int* __restrict__ histS,      // [NB_B][nch] scanned (bucket-major)
    unsigned* __restrict__ metaC,
    int* __restrict__ row_ptr, int nnz, int nch)
{
    __shared__ unsigned cc[CAP];        // 48 KB
    __shared__ int cnt[256], scn[256], cur[256];

    int b    = blockIdx.x;
    int base = histS[(size_t)b * nch];
    int end  = (b + 1 < gridDim.x) ? histS[(size_t)(b + 1) * nch] : nnz;
    int n    = min(end - base, CAP);

    cnt[threadIdx.x] = 0;
    __syncthreads();
    for (int i = threadIdx.x; i < n; i += 256) {
        unsigned m = metaC[base + i];
        cc[i] = m;
        atomicAdd(&cnt[m >> 24], 1);
    }
    __syncthreads();
    int v = cnt[threadIdx.x];
    scn[threadIdx.x] = v;
    __syncthreads();
    for (int off = 1; off < 256; off <<= 1) {
        int u = (threadIdx.x >= off) ? scn[threadIdx.x - off] : 0;
        __syncthreads();
        scn[threadIdx.x] += u;
        __syncthreads();
    }
    int excl = scn[threadIdx.x] - v;

    int r0 = b * B_ROWS;
    int nr = min(B_ROWS, N_NODES - r0);
    if (threadIdx.x < nr) row_ptr[r0 + threadIdx.x] = base + excl;
    if (b == gridDim.x - 1 && threadIdx.x == 0) row_ptr[N_NODES] = nnz;

    cur[threadIdx.x] = excl;
    __syncthreads();
    for (int i = threadIdx.x; i < n; i += 256) {
        unsigned m = cc[i];
        int d = atomicAdd(&cur[m >> 24], 1);
        metaC[base + d] = m;
    }
}

// ---------------------------------------------------------------------------
// emb prep: out[:,0:64] = emb AND fp8 gather table, one pass over emb.
// ---------------------------------------------------------------------------
__global__ __launch_bounds__(256) void emb_prep_kernel(
    const float4* __restrict__ emb, unsigned* __restrict__ tblF8,
    float* __restrict__ out)
{
    int i = blockIdx.x * 256 + threadIdx.x;
    if (i >= N_NODES * 16) return;
    float4 x = emb[i];
    int n = i >> 4, j = i & 15;
    f32x4 xv = {x.x, x.y, x.z, x.w};
    __builtin_nontemporal_store(xv, (f32x4*)(out + (size_t)n * 192 + j * 4));
    tblF8[i] = f8pack4(x.x, x.y, x.z, x.w);
}

// ---------------------------------------------------------------------------
// CSR SpMM, fp8 table + 4B records, 2x-unrolled edge loop for MLP:
// one wave per row, 8 edge slots x 8 dim-eighths; fp32 accumulate;
// bf16 nontemporal side store.
// ---------------------------------------------------------------------------
__global__ __launch_bounds__(256) void spmm_csr_f8_kernel(
    const uint2* __restrict__ tbl8,       // fp8 rows of 64 B
    const int*   __restrict__ row_ptr,
    const unsigned* __restrict__ metaC,   // col | v5<<19 | lr<<24
    ushort_t*    __restrict__ side_b16)   // bf16 [N][64]
{
    int wid = (blockIdx.x * 256 + threadIdx.x) >> 6;
    if (wid >= N_NODES) return;
    int lane = threadIdx.x & 63;
    int g = lane >> 3;
    int q = lane & 7;

    int start = row_ptr[wid];
    int end   = row_ptr[wid + 1];

    float acc[8];
#pragma unroll
    for (int i = 0; i < 8; ++i) acc[i] = 0.f;

    int j = start + g;
    // pair loop: 2 edges in flight per lane-slot
    for (; j + 8 < end; j += 16) {
        unsigned mc0 = metaC[j];
        unsigned mc1 = metaC[j + 8];
        float v0 = (float)((mc0 >> 19) & 31u) * VQ_INV;
        float v1 = (float)((mc1 >> 19) & 31u) * VQ_INV;
        uint2 x0 = tbl8[(size_t)(mc0 & COL_MASK) * 8 + q];
        uint2 x1 = tbl8[(size_t)(mc1 & COL_MASK) * 8 + q];
        f32x2 a0 = f8cvt2<false>(x0.x), a1 = f8cvt2<true>(x0.x);
        f32x2 a2 = f8cvt2<false>(x0.y), a3 = f8cvt2<true>(x0.y);
        f32x2 b0 = f8cvt2<false>(x1.x), b1 = f8cvt2<true>(x1.x);
        f32x2 b2 = f8cvt2<false>(x1.y), b3 = f8cvt2<true>(x1.y);
        acc[0] += v0 * a0[0]; acc[1] += v0 * a0[1];
        acc[2] += v0 * a1[0]; acc[3] += v0 * a1[1];
        acc[4] += v0 * a2[0]; acc[5] += v0 * a2[1];
        acc[6] += v0 * a3[0]; acc[7] += v0 * a3[1];
        acc[0] += v1 * b0[0]; acc[1] += v1 * b0[1];
        acc[2] += v1 * b1[0]; acc[3] += v1 * b1[1];
        acc[4] += v1 * b2[0]; acc[5] += v1 * b2[1];
        acc[6] += v1 * b3[0]; acc[7] += v1 * b3[1];
    }
    if (j < end) {
        unsigned mc = metaC[j];
        float v = (float)((mc >> 19) & 31u) * VQ_INV;
        uint2 x = tbl8[(size_t)(mc & COL_MASK) * 8 + q];
        f32x2 f0 = f8cvt2<false>(x.x), f1 = f8cvt2<true>(x.x);
        f32x2 f2 = f8cvt2<false>(x.y), f3 = f8cvt2<true>(x.y);
        acc[0] += v * f0[0]; acc[1] += v * f0[1];
        acc[2] += v * f1[0]; acc[3] += v * f1[1];
        acc[4] += v * f2[0]; acc[5] += v * f2[1];
        acc[6] += v * f3[0]; acc[7] += v * f3[1];
    }
#pragma unroll
    for (int off = 8; off <= 32; off <<= 1) {
#pragma unroll
        for (int i = 0; i < 8; ++i) acc[i] += __shfl_xor(acc[i], off);
    }
    if (g == 0) {
        u32x4 pk;
        pk.x = ((unsigned)f2b(acc[1]) << 16) | f2b(acc[0]);
        pk.y = ((unsigned)f2b(acc[3]) << 16) | f2b(acc[2]);
        pk.z = ((unsigned)f2b(acc[5]) << 16) | f2b(acc[4]);
        pk.w = ((unsigned)f2b(acc[7]) << 16) | f2b(acc[6]);
        __builtin_nontemporal_store(pk, (u32x4*)(side_b16 + (size_t)wid * DIM + q * 8));
    }
}

// ---------------------------------------------------------------------------
// MFMA dense layer: y = leaky(s@gw.T + gb + p@bw.T + bb), s=side+e, p=side*e.
// side is bf16. Layer 0 reads ego fp32 (emb); layer 1 reads bf16 ego table.
// Layer 0 epilogue writes next-layer tables: bf16 (dense) + fp8 (gather).
// ---------------------------------------------------------------------------
template<bool EGO_F32, bool WRITE_TBL>
__global__ __launch_bounds__(256) void dense_mfma_kernel(
    const float*   __restrict__ ego_f32,    // EGO_F32
    const ushort_t* __restrict__ ego_b16,   // !EGO_F32
    const ushort_t* __restrict__ side_b16,
    const float* __restrict__ gw, const float* __restrict__ gb,
    const float* __restrict__ bw, const float* __restrict__ bb,
    ushort_t* __restrict__ tblb_out,        // bf16 ego out (layer 0)
    uchar_t*  __restrict__ tblf8_out,       // fp8 ego out (layer 0)
    float* __restrict__ out, int out_col)
{
    __shared__ ushort_t s_lds[64][72];      // 9 KB (pad 8 bf16 = 16 B)
    __shared__ ushort_t p_lds[64][72];      // 9 KB

    const int tid  = threadIdx.x;
    const int lane = tid & 63;
    const int wv   = tid >> 6;
    const int lrow = lane & 15;
    const int kgrp = lane >> 4;

    // B-fragments (weights) + bias, loaded once
    bf16x8 wgf[4][2], wbf[4][2];
    float  biasv[4];
#pragma unroll
    for (int t = 0; t < 4; ++t) {
        int o = 16 * t + lrow;
#pragma unroll
        for (int h = 0; h < 2; ++h) {
            const float* pg = gw + (size_t)o * DIM + 32 * h + 8 * kgrp;
            const float* pb = bw + (size_t)o * DIM + 32 * h + 8 * kgrp;
            ushort_t tg[8], tb[8];
#pragma unroll
            for (int i = 0; i < 8; ++i) { tg[i] = f2b(pg[i]); tb[i] = f2b(pb[i]); }
            wgf[t][h] = *(const bf16x8*)tg;
            wbf[t][h] = *(const bf16x8*)tb;
        }
        biasv[t] = gb[o] + bb[o];
    }

    for (int tile0 = blockIdx.x * 64; tile0 < N_NODES; tile0 += gridDim.x * 64) {
        int nmax = min(64, N_NODES - tile0);
        __syncthreads();
        // ---- stage s,p (bf16) for 64 nodes: thread = (row, dim-quarter) ----
        {
            int r  = tid >> 2;
            int d0 = (tid & 3) * 16;
            if (r < nmax) {
                const uint4* sp = (const uint4*)(side_b16 + (size_t)(tile0 + r) * DIM + d0);
                uint4 sb0 = sp[0], sb1 = sp[1];
                float sv[16] = { blo(sb0.x), bhi(sb0.x), blo(sb0.y), bhi(sb0.y),
                                 blo(sb0.z), bhi(sb0.z), blo(sb0.w), bhi(sb0.w),
                                 blo(sb1.x), bhi(sb1.x), blo(sb1.y), bhi(sb1.y),
                                 blo(sb1.z), bhi(sb1.z), blo(sb1.w), bhi(sb1.w) };
                float ev[16];
                if (EGO_F32) {
                    const float4* ep = (const float4*)(ego_f32 + (size_t)(tile0 + r) * DIM + d0);
                    float4 e0 = ep[0], e1 = ep[1], e2 = ep[2], e3 = ep[3];
                    float tmp[16] = { e0.x, e0.y, e0.z, e0.w, e1.x, e1.y, e1.z, e1.w,
                                      e2.x, e2.y, e2.z, e2.w, e3.x, e3.y, e3.z, e3.w };
#pragma unroll
                    for (int i = 0; i < 16; ++i) ev[i] = tmp[i];
                } else {
                    const uint4* ep = (const uint4*)(ego_b16 + (size_t)(tile0 + r) * DIM + d0);
                    uint4 e0 = ep[0], e1 = ep[1];
                    float tmp[16] = { blo(e0.x), bhi(e0.x), blo(e0.y), bhi(e0.y),
                                      blo(e0.z), bhi(e0.z), blo(e0.w), bhi(e0.w),
                                      blo(e1.x), bhi(e1.x), blo(e1.y), bhi(e1.y),
                                      blo(e1.z), bhi(e1.z), blo(e1.w), bhi(e1.w) };
#pragma unroll
                    for (int i = 0; i < 16; ++i) ev[i] = tmp[i];
                }
                unsigned spk[8], ppk[8];
#pragma unroll
                for (int i = 0; i < 8; ++i) {
                    float a  = sv[2*i]   + ev[2*i];
                    float b2 = sv[2*i+1] + ev[2*i+1];
                    float c  = sv[2*i]   * ev[2*i];
                    float d  = sv[2*i+1] * ev[2*i+1];
                    spk[i] = ((unsigned)f2b(b2) << 16) | f2b(a);
                    ppk[i] = ((unsigned)f2b(d)  << 16) | f2b(c);
                }
                *(uint4*)&s_lds[r][d0]     = make_uint4(spk[0], spk[1], spk[2], spk[3]);
                *(uint4*)&s_lds[r][d0 + 8] = make_uint4(spk[4], spk[5], spk[6], spk[7]);
                *(uint4*)&p_lds[r][d0]     = make_uint4(ppk[0], ppk[1], ppk[2], ppk[3]);
                *(uint4*)&p_lds[r][d0 + 8] = make_uint4(ppk[4], ppk[5], ppk[6], ppk[7]);
            }
        }
        __syncthreads();

        // ---- compute: wave wv owns nodes tile0 + wv*16 .. +15 ----
        const int arow = wv * 16 + lrow;
        bf16x8 sf[2], pf[2];
        sf[0] = *(const bf16x8*)&s_lds[arow][8 * kgrp];
        sf[1] = *(const bf16x8*)&s_lds[arow][32 + 8 * kgrp];
        pf[0] = *(const bf16x8*)&p_lds[arow][8 * kgrp];
        pf[1] = *(const bf16x8*)&p_lds[arow][32 + 8 * kgrp];

        f32x4 acc[4];
#pragma unroll
        for (int t = 0; t < 4; ++t)
            acc[t] = (f32x4){biasv[t], biasv[t], biasv[t], biasv[t]};

#pragma unroll
        for (int h = 0; h < 2; ++h) {
#pragma unroll
            for (int t = 0; t < 4; ++t) {
                acc[t] = __builtin_amdgcn_mfma_f32_16x16x32_bf16(sf[h], wgf[t][h], acc[t], 0, 0, 0);
                acc[t] = __builtin_amdgcn_mfma_f32_16x16x32_bf16(pf[h], wbf[t][h], acc[t], 0, 0, 0);
            }
        }

        // ---- epilogue: leaky, row-norm (16-lane group reduce), stores ----
        float y[4][4];
        float ssr[4] = {0.f, 0.f, 0.f, 0.f};
#pragma unroll
        for (int t = 0; t < 4; ++t)
#pragma unroll
            for (int rg = 0; rg < 4; ++rg) {
                float v = acc[t][rg];
                v = v > 0.f ? v : 0.2f * v;
                y[t][rg] = v;
                ssr[rg] += v * v;
            }
#pragma unroll
        for (int off = 1; off <= 8; off <<= 1)
#pragma unroll
            for (int rg = 0; rg < 4; ++rg)
                ssr[rg] += __shfl_xor(ssr[rg], off);

#pragma unroll
        for (int rg = 0; rg < 4; ++rg) {
            int node = tile0 + wv * 16 + kgrp * 4 + rg;
            if (node < N_NODES) {
                float inv = 1.0f / fmaxf(sqrtf(ssr[rg]), 1e-12f);
                float* orow = out + (size_t)node * 192 + out_col;
#pragma unroll
                for (int t = 0; t < 4; ++t)
                    orow[t * 16 + lrow] = y[t][rg] * inv;
                if (WRITE_TBL) {
#pragma unroll
                    for (int t = 0; t < 4; ++t) {
                        tblb_out[(size_t)node * DIM + t * 16 + lrow] = f2b(y[t][rg]);
                        tblf8_out[(size_t)node * DIM + t * 16 + lrow] = (uchar_t)f8pack1(y[t][rg]);
                    }
                }
            }
        }
    }
}

// ---------------------------------------------------------------------------
// Fallback path (ws too small): atomic SpMM + fp32 dense.
// ---------------------------------------------------------------------------
__global__ __launch_bounds__(256) void spmm_atomic_kernel(
    const float* __restrict__ ego,
    const int*   __restrict__ rows,
    const int*   __restrict__ cols,
    const float* __restrict__ vals,
    float*       __restrict__ side,
    int nnz)
{
    long long i = (long long)blockIdx.x * blockDim.x + threadIdx.x;
    long long total = (long long)nnz * DIM;
    if (i >= total) return;
    int e = (int)(i >> 6);
    int d = (int)(i & 63);
    atomicAdd(side + ((size_t)rows[e] * DIM + d), vals[e] * ego[(size_t)cols[e] * DIM + d]);
}

template<bool WRITE_F32>
__global__ __launch_bounds__(256) void dense_norm_kernel(
    const float* __restrict__ ego_in,
    const float* __restrict__ side,
    const float* __restrict__ gw, const float* __restrict__ gb,
    const float* __restrict__ bw, const float* __restrict__ bb,
    float* __restrict__ ego_out,
    float* __restrict__ out, int out_col)
{
    __shared__ float s_lds[32][DIM];
    __shared__ float p_lds[32][DIM];

    const int o  = threadIdx.x & 63;
    const int wv = threadIdx.x >> 6;

    float w0[DIM], w1[DIM];
#pragma unroll
    for (int k4 = 0; k4 < DIM / 4; ++k4) {
        float4 a = *(const float4*)(gw + (size_t)o * DIM + k4 * 4);
        float4 b = *(const float4*)(bw + (size_t)o * DIM + k4 * 4);
        w0[4*k4+0] = a.x; w0[4*k4+1] = a.y; w0[4*k4+2] = a.z; w0[4*k4+3] = a.w;
        w1[4*k4+0] = b.x; w1[4*k4+1] = b.y; w1[4*k4+2] = b.z; w1[4*k4+3] = b.w;
    }
    const float bias = gb[o] + bb[o];

    for (int tile = blockIdx.x * 32; tile < N_NODES; tile += gridDim.x * 32) {
        int nmax = min(32, N_NODES - tile);
        __syncthreads();
        const float4* sd4 = (const float4*)side + (size_t)tile * 16;
        const float4* eg4 = (const float4*)ego_in + (size_t)tile * 16;
        float4* s4 = (float4*)&s_lds[0][0];
        float4* p4 = (float4*)&p_lds[0][0];
        for (int i = threadIdx.x; i < nmax * 16; i += 256) {
            float4 e = eg4[i], s = sd4[i];
            s4[i] = make_float4(s.x+e.x, s.y+e.y, s.z+e.z, s.w+e.w);
            p4[i] = make_float4(s.x*e.x, s.y*e.y, s.z*e.z, s.w*e.w);
        }
        __syncthreads();
        for (int n = wv; n < nmax; n += 4) {
            const float4* srow = (const float4*)&s_lds[n][0];
            const float4* prow = (const float4*)&p_lds[n][0];
            float a0 = bias, a1 = 0.f, a2 = 0.f, a3 = 0.f;
#pragma unroll
            for (int k4 = 0; k4 < 16; ++k4) {
                float4 sk = srow[k4];
                float4 pk = prow[k4];
                a0 = fmaf(sk.x, w0[4*k4+0], a0); a1 = fmaf(pk.x, w1[4*k4+0], a1);
                a2 = fmaf(sk.y, w0[4*k4+1], a2); a3 = fmaf(pk.y, w1[4*k4+1], a3);
                a0 = fmaf(sk.z, w0[4*k4+2], a0); a1 = fmaf(pk.z, w1[4*k4+2], a1);
                a2 = fmaf(sk.w, w0[4*k4+3], a2); a3 = fmaf(pk.w, w1[4*k4+3], a3);
            }
            float acc = (a0 + a1) + (a2 + a3);
            float y = acc > 0.f ? acc : 0.2f * acc;
            size_t node = (size_t)(tile + n);
            if (WRITE_F32) ego_out[node * DIM + o] = y;
            float ss = y * y;
#pragma unroll
            for (int off = 32; off > 0; off >>= 1)
                ss += __shfl_xor(ss, off);
            float inv = 1.0f / fmaxf(sqrtf(ss), 1e-12f);
            out[node * 192 + out_col + o] = y * inv;
        }
    }
}

__global__ __launch_bounds__(256) void copy_emb_kernel(
    const float4* __restrict__ emb, float4* __restrict__ out)
{
    int i = blockIdx.x * blockDim.x + threadIdx.x;
    if (i >= N_NODES * 16) return;
    int n = i >> 4, j = i & 15;
    out[(size_t)n * 48 + j] = emb[i];
}

extern "C" void kernel_launch(void* const* d_in, const int* in_sizes, int n_in,
                              void* d_out, int out_size, void* d_ws, size_t ws_size,
                              hipStream_t stream)
{
    const float* emb   = (const float*)d_in[0];
    const float* gc_w0 = (const float*)d_in[1];
    const float* gc_b0 = (const float*)d_in[2];
    const float* bi_w0 = (const float*)d_in[3];
    const float* bi_b0 = (const float*)d_in[4];
    const float* gc_w1 = (const float*)d_in[5];
    const float* gc_b1 = (const float*)d_in[6];
    const float* bi_w1 = (const float*)d_in[7];
    const float* bi_b1 = (const float*)d_in[8];
    const int*   rows  = (const int*)d_in[9];
    const int*   cols  = (const int*)d_in[10];
    const float* vals  = (const float*)d_in[11];
    const int    nnz   = in_sizes[9];

    float* out = (float*)d_out;

    const int nch = (nnz + CHUNK - 1) / CHUNK;            // chunks
    const int n2  = NB_B * nch;                           // hist entries
    const size_t hist_al = (((size_t)n2 * sizeof(int)) + 63) & ~size_t(63);
    const size_t tbl_al  = (((size_t)N_NODES * DIM) + 63) & ~size_t(63);  // fp8 table bytes

    // ---- workspace layout ----
    char* ws = (char*)d_ws;
    size_t off = 0;
    auto alloc = [&](size_t bytes) { char* p = ws + off; off += (bytes + 63) & ~size_t(63); return p; };
    // sideRegion: fallback = fp32 side (N*DIM*4). CSR path: low half bf16 side,
    // high half metaC (nnz*4 <= N*DIM*2 guarded below).
    char* sideRegion = alloc((size_t)N_NODES * DIM * sizeof(float));
    float*    side_f32 = (float*)sideRegion;
    ushort_t* side_b16 = (ushort_t*)sideRegion;
    unsigned* metaC    = (unsigned*)(sideRegion + (size_t)N_NODES * DIM * sizeof(ushort_t));
    ushort_t* ego1_b = (ushort_t*)alloc((size_t)N_NODES * DIM * sizeof(ushort_t));
    // Union region: build-phase {histT, histA}; post-build {emb_f8 / ego1_f8 (time-shared)}
    size_t u_build = 2 * hist_al;
    char* U = alloc(u_build > tbl_al ? u_build : tbl_al);
    int* histT = (int*)U;
    int* histA = (int*)(U + hist_al);
    int* curT  = histT;                                   // reuse after transpose 1
    uchar_t* emb_f8  = (uchar_t*)U;                       // alive: emb_prep..spmm0
    uchar_t* ego1_f8 = (uchar_t*)U;                       // alive: dense0..spmm1
    int* row_ptr = (int*)alloc((size_t)(N_NODES + 1) * sizeof(int));
    int* bsum    = (int*)alloc(2048 * sizeof(int));
    // fallback needs ego1 scratch: reuse U when csr disabled (nnz*4B each for... )
    const bool csr_ok = (off <= ws_size) && (nnz <= 11000000) &&
                        ((size_t)nnz * 4 <= (size_t)N_NODES * DIM * 2);  // metaC fits

    const int spmm_blocks  = (N_NODES * 64 + 255) / 256;
    const int dense_blocks = (N_NODES + 63) / 64;

    if (csr_ok) {
        // ---- bucketed CSR build ----
        binhist_kernel<<<nch, 256, 0, stream>>>(rows, histT, nnz);
        {   // histT[nch][NB_B] -> histA[NB_B][nch]
            dim3 g((NB_B + 31) / 32, (nch + 31) / 32);
            transpose_kernel<<<g, 256, 0, stream>>>(histT, histA, nch, NB_B);
        }
        const int nsb = (n2 + SCAN_B - 1) / SCAN_B;       // <= 2048
        scan1_kernel<<<nsb, 256, 0, stream>>>(histA, bsum, n2);
        scan2_kernel<<<1, 256, 0, stream>>>(bsum, nsb);
        scan3_kernel<<<(n2 + 255) / 256, 256, 0, stream>>>(histA, bsum, n2);
        {   // histA[NB_B][nch] (scanned) -> curT[nch][NB_B]
            dim3 g((nch + 31) / 32, (NB_B + 31) / 32);
            transpose_kernel<<<g, 256, 0, stream>>>(histA, curT, NB_B, nch);
        }
        binscatter_kernel<<<nch, 512, 0, stream>>>(rows, cols, vals, curT, metaC, nnz);
        bucketfinal_kernel<<<NB_B, 256, 0, stream>>>(histA, metaC, row_ptr, nnz, nch);

        // emb -> out[:,0:64] + fp8 gather table (hist region now dead)
        emb_prep_kernel<<<(N_NODES * 16 + 255) / 256, 256, 0, stream>>>(
            (const float4*)emb, (unsigned*)emb_f8, out);

        // ---- layer 0 ----
        spmm_csr_f8_kernel<<<spmm_blocks, 256, 0, stream>>>(
            (const uint2*)emb_f8, row_ptr, metaC, side_b16);
        dense_mfma_kernel<true, true><<<dense_blocks, 256, 0, stream>>>(
            emb, nullptr, side_b16, gc_w0, gc_b0, bi_w0, bi_b0,
            ego1_b, ego1_f8, out, DIM);           // ego1_f8 overwrites emb_f8 (dead)

        // ---- layer 1 ----
        spmm_csr_f8_kernel<<<spmm_blocks, 256, 0, stream>>>(
            (const uint2*)ego1_f8, row_ptr, metaC, side_b16);
        dense_mfma_kernel<false, false><<<dense_blocks, 256, 0, stream>>>(
            nullptr, ego1_b, side_b16, gc_w1, gc_b1, bi_w1, bi_b1,
            nullptr, nullptr, out, 2 * DIM);
    } else {
        // ---- fallback: atomic SpMM + fp32 dense ----
        // ego1 scratch: use ego1_b + U region (contiguous alloc order makes
        // ego1_b..U span >= N*DIM*4 bytes when csr path disabled)
        float* ego1 = (float*)ego1_b;
        const size_t side_bytes = (size_t)N_NODES * DIM * sizeof(float);
        const long long total = (long long)nnz * DIM;
        const int ab = (int)((total + 255) / 256);
        const int db = (N_NODES + 31) / 32;
        hipMemsetAsync(side_f32, 0, side_bytes, stream);
        spmm_atomic_kernel<<<ab, 256, 0, stream>>>(emb, rows, cols, vals, side_f32, nnz);
        dense_norm_kernel<true><<<db, 256, 0, stream>>>(
            emb, side_f32, gc_w0, gc_b0, bi_w0, bi_b0, ego1, out, DIM);
        hipMemsetAsync(side_f32, 0, side_bytes, stream);
        spmm_atomic_kernel<<<ab, 256, 0, stream>>>(ego1, rows, cols, vals, side_f32, nnz);
        dense_norm_kernel<false><<<db, 256, 0, stream>>>(
            ego1, side_f32, gc_w1, gc_b1, bi_w1, bi_b1, nullptr, out, 2 * DIM);
        copy_emb_kernel<<<(N_NODES * 16 + 255) / 256, 256, 0, stream>>>(
            (const float4*)emb, (float4*)out);
    }
}